// Round 9
// baseline (1495.530 us; speedup 1.0000x reference)
//
#include <hip/hip_runtime.h>
#include <math.h>

#define NPTS 8192
#define NPS  (NPTS*32)
#define XPKSTG 262144   // shorts per stage x-frag buffer (512 KB)

typedef __attribute__((ext_vector_type(8))) short bf16x8;
typedef __attribute__((ext_vector_type(4))) float f32x4;

__device__ __forceinline__ float tanh_fast(float x) {
  float e = __expf(2.0f*x);
  return 1.0f - 2.0f*__builtin_amdgcn_rcpf(e + 1.0f);
}
__device__ __forceinline__ unsigned short bf16h(float x) {
  unsigned u = __float_as_uint(x);
  return (unsigned short)((u + 0x7FFFu + ((u>>16)&1u)) >> 16);
}
__device__ __forceinline__ float bf16f(unsigned short h) {
  return __uint_as_float(((unsigned)h)<<16);
}
__device__ __forceinline__ bf16x8 pack_hi(const float* base) {
  bf16x8 H;
  #pragma unroll
  for (int jj = 0; jj < 4; ++jj) {
    float2 q = *(const float2*)(base + 2*jj);
    H[2*jj]   = (short)bf16h(q.x);
    H[2*jj+1] = (short)bf16h(q.y);
  }
  return H;
}

// ---------------- prologue kernels ----------------

__global__ void kA_softmax(const float* __restrict__ gE, short* __restrict__ ApkH,
                           short* __restrict__ ApkL) {
  __shared__ float gn[16];
  __shared__ float red[256];
  int n = blockIdx.x, t = threadIdx.x;
  if (t < 16) gn[t] = gE[n*16 + t];
  __syncthreads();
  float e0, e1;
  {
    float d = 0.f;
    #pragma unroll
    for (int dd = 0; dd < 16; ++dd) d = fmaf(gn[dd], gE[t*16 + dd], d);
    e0 = __expf(fmaxf(d, 0.f));
  }
  {
    float d = 0.f;
    #pragma unroll
    for (int dd = 0; dd < 16; ++dd) d = fmaf(gn[dd], gE[(t+256)*16 + dd], d);
    e1 = __expf(fmaxf(d, 0.f));
  }
  red[t] = e0 + e1;
  __syncthreads();
  for (int off = 128; off > 0; off >>= 1) {
    if (t < off) red[t] += red[t+off];
    __syncthreads();
  }
  float inv = __builtin_amdgcn_rcpf(red[0]);
  int nt = n >> 4;
  #pragma unroll
  for (int half = 0; half < 2; ++half) {
    int k = t + half*256;
    float v = (half ? e1 : e0) * inv;
    int c = k >> 5, g = (k>>3)&3, j = k&7;
    int l = g*16 + (n&15);
    size_t off2 = ((size_t)(nt*16 + c)*64 + l)*8 + j;
    unsigned short hb = bf16h(v);
    ApkH[off2] = (short)hb;
    ApkL[off2] = (short)bf16h(v - bf16f(hb));
  }
}

__global__ __launch_bounds__(256) void kAwB(const float* __restrict__ gE,
                      const float* __restrict__ gWpool,
                      const float* __restrict__ gbpool,
                      unsigned* __restrict__ awb, float* __restrict__ ab) {
  __shared__ float gn[16];
  int n = blockIdx.x, t = threadIdx.x;
  if (t < 16) gn[t] = gE[n*16 + t];
  __syncthreads();
  #pragma unroll
  for (int r = 0; r < 4; ++r) {
    int e = t + r*256;
    int q = e >> 5, o = e & 31;
    float s0 = 0.f, s1 = 0.f;
    #pragma unroll
    for (int d = 0; d < 16; ++d) {
      float g = gn[d];
      s0 = fmaf(g, gWpool[d*2048 + (2*q)*32 + o], s0);
      s1 = fmaf(g, gWpool[d*2048 + (2*q+1)*32 + o], s1);
    }
    awb[(size_t)n*1024 + e] = (unsigned)bf16h(s0) | ((unsigned)bf16h(s1) << 16);
  }
  if (t < 32) {
    float s = 0.f;
    #pragma unroll
    for (int d = 0; d < 16; ++d) s = fmaf(gn[d], gbpool[d*32 + t], s);
    ab[n*32 + t] = s;
  }
}

__global__ void kPackGW(const float* __restrict__ gWout, short* __restrict__ GpkH,
                        short* __restrict__ GpkL) {
  int idx = blockIdx.x*256 + threadIdx.x;   // 32768
  int j = idx & 7, l = (idx>>3)&63, tl = idx>>9;
  int col = tl*16 + (l&15);
  int k = ((l>>4)&3)*8 + j;
  float v = gWout[k*1024 + col];
  unsigned short hb = bf16h(v);
  GpkH[idx] = (short)hb;
  GpkL[idx] = (short)bf16h(v - bf16f(hb));
}

__global__ void kPackW(const float* __restrict__ fWin, const float* __restrict__ fWmid,
                       const float* __restrict__ fWout, const float* __restrict__ gWin,
                       short* __restrict__ WpkH, short* __restrict__ WpkL) {
  int idx = blockIdx.x*256 + threadIdx.x;   // 5120
  if (idx >= 5120) return;
  int j = idx & 7, l = (idx>>3)&63, T = idx>>9;
  int k = ((l>>4)&3)*8 + j;
  const float* M; int cols, tl;
  if (T < 2)      { M = fWin;  cols = 32; tl = T;   }
  else if (T < 4) { M = fWmid; cols = 32; tl = T-2; }
  else if (T < 8) { M = fWout; cols = 64; tl = T-4; }
  else            { M = gWin;  cols = 32; tl = T-8; }
  float v = M[k*cols + tl*16 + (l&15)];
  unsigned short hb = bf16h(v);
  WpkH[idx] = (short)hb;
  WpkL[idx] = (short)bf16h(v - bf16f(hb));
}

__global__ void kDX(const float* __restrict__ cb, const float* __restrict__ cc2,
                    const float* __restrict__ cd3, float* __restrict__ dX) {
  int idx = blockIdx.x*256 + threadIdx.x;       // 557056
  int slot = idx >> 14;
  int rem = idx & 16383;
  int p = rem >> 1, i = rem & 1;
  float v;
  if (slot == 0) {
    v = cb[p*22 + i];
  } else {
    int s1 = slot - 1;
    int k = s1 / 3, j = s1 - 3*k;
    float frac = (float)(j+1) * (1.0f/3.0f);
    if (j == 2) frac = 1.0f;
    int base = p*22 + k*2 + i;
    v = cb[base] + (cc2[base] + cd3[base]*frac)*frac;
  }
  dX[idx] = v;
}

__global__ void kInit(const float* __restrict__ ca, const float* __restrict__ Wh,
                      const float* __restrict__ bh, const float* __restrict__ Wz,
                      const float* __restrict__ bz, float* __restrict__ h,
                      float* __restrict__ z) {
  int idx = blockIdx.x*256 + threadIdx.x;       // 262144
  int c = idx & 31, p = idx >> 5;
  float x0 = ca[p*22 + 0], x1 = ca[p*22 + 1];
  h[idx] = fmaf(x0, Wh[c], fmaf(x1, Wh[32+c], bh[c]));
  z[idx] = fmaf(x0, Wz[c], fmaf(x1, Wz[32+c], bz[c]));
}

// initial xrel -> f32 + packed hi frags into stage-0 buffer
__global__ void kXrel0(const float* __restrict__ z, const float* __restrict__ gWin,
                       const float* __restrict__ gbin, float* __restrict__ xrel,
                       short* __restrict__ xpk0) {
  __shared__ float zl[8][32];
  int t = threadIdx.x, pl = t >> 5, o = t & 31;
  int p = blockIdx.x*8 + pl;
  zl[pl][o] = z[p*32 + o];
  __syncthreads();
  float s = gbin[o];
  #pragma unroll
  for (int i = 0; i < 32; ++i) s = fmaf(zl[pl][i], gWin[i*32 + o], s);
  float xr = fmaxf(s, 0.f);
  xrel[p*32 + o] = xr;
  int b = p >> 9, m = p & 511;
  int c = m >> 5, rr = m & 31;
  int lane = (rr>>3)*16 + (o&15);
  int tt = o >> 4;
  size_t off = (((size_t)(b*16 + c)*2 + tt)*64 + lane)*8 + (rr&7);
  xpk0[off] = (short)bf16h(xr);
}

// ---------------- persistent scan kernel ----------------

// Relaxed barrier: no acquire fence, L2 never invalidated. Cross-block x-frags
// use buffer renaming (unique buffer per stage): producers store write-through
// (sc0 sc1), consumers use NORMAL cached loads of never-before-cached lines.
__device__ __forceinline__ void batch_barrier(unsigned* __restrict__ cnt, unsigned target) {
  __syncthreads();   // drains vmcnt (write-through stores complete) per wave
  if (threadIdx.x == 0) {
    __hip_atomic_fetch_add(cnt, 1u, __ATOMIC_RELAXED, __HIP_MEMORY_SCOPE_AGENT);
    unsigned guard = 0;
    while (__hip_atomic_load(cnt, __ATOMIC_RELAXED, __HIP_MEMORY_SCOPE_AGENT) < target) {
      if (++guard > (1u<<22)) break;   // bounded: fail visibly, never hang
      __builtin_amdgcn_s_sleep(2);
    }
  }
  __syncthreads();
}

// grid 512 (b x ntile), 512 thr = 8 waves, 2 blocks/CU (all co-resident).
__global__ __launch_bounds__(512, 4) void kPersist(
    const unsigned* __restrict__ awb, const float* __restrict__ ab,
    const float* __restrict__ dX, const float* __restrict__ h0,
    float* __restrict__ zio, const float* __restrict__ xrel0,
    short* __restrict__ xpk,
    const short* __restrict__ ApkH, const short* __restrict__ ApkL,
    const short* __restrict__ GpkH, const short* __restrict__ GpkL,
    const short* __restrict__ WpkH, const short* __restrict__ WpkL,
    const float* __restrict__ fbin, const float* __restrict__ fbmid,
    const float* __restrict__ fbout, const float* __restrict__ gbin,
    const float* __restrict__ gbout, unsigned* __restrict__ bar)
{
  __shared__ float scrA[8][16][32];
  __shared__ float bGl[1024];
  __shared__ float HS[16*34], X1[16*34], X2[16*34], PLb[16*34];
  __shared__ float XR[16*36], AG[16*36];
  __shared__ float DHT[32*20];
  __shared__ float DZ[16*33];
  __shared__ short WH_l[5120], WL_l[5120];
  __shared__ float bF[160];
  __shared__ float abS[512];
  __shared__ float hS[512], zS[512], khS[3*512], kzS[3*512];

  int t = threadIdx.x;
  int pl = t >> 5, o = t & 31;
  int w = t >> 6, l = t & 63;
  int ll = l & 15, lg = l >> 4;
  int bid = blockIdx.x;
  int xcd = bid & 7, sub = (bid >> 3) & 3, b = bid >> 5;
  int ntile = xcd*4 + sub;
  int pgbase = b*512 + ntile*16;
  unsigned* cnt = bar + b*64;

  // ---- once: stage-invariant data ----
  bGl[t] = gbout[t]; bGl[t+512] = gbout[t+512];
  for (int j = t; j < 5120; j += 512) { WH_l[j] = WpkH[j]; WL_l[j] = WpkL[j]; }
  if (t < 32) bF[t] = fbin[t];
  else if (t < 64) bF[t] = fbmid[t-32];
  else if (t < 128) bF[t] = fbout[t-64];
  else if (t < 160) bF[t] = gbin[t-128];
  abS[t] = ab[(size_t)(ntile*16 + pl)*32 + o];
  bf16x8 gHreg[8], gLreg[8];
  #pragma unroll
  for (int u = 0; u < 8; ++u) {
    gHreg[u] = *(const bf16x8*)(GpkH + ((size_t)(w*8 + u)*64 + l)*8);
    gLreg[u] = *(const bf16x8*)(GpkL + ((size_t)(w*8 + u)*64 + l)*8);
  }
  bf16x8 aH2[2], aL2[2];
  #pragma unroll
  for (int cc = 0; cc < 2; ++cc) {
    size_t aoff = ((size_t)(ntile*16 + w*2 + cc)*64 + l)*8;
    aH2[cc] = *(const bf16x8*)(ApkH + aoff);
    aL2[cc] = *(const bf16x8*)(ApkL + aoff);
  }
  // pool weights for THIS thread's (pl,o) output, resident for all 44 stages
  unsigned awR[32];
  {
    const unsigned* awp = awb + (size_t)(ntile*16 + pl)*1024 + o;
    #pragma unroll
    for (int q = 0; q < 16; ++q) {
      awR[q]      = awp[q*32];
      awR[16 + q] = awp[512 + q*32];
    }
  }
  hS[t] = h0[(size_t)pgbase*32 + t];
  zS[t] = zio[(size_t)pgbase*32 + t];
  XR[pl*36 + o] = xrel0[(size_t)(pgbase + pl)*32 + o];
  __syncthreads();

  #pragma unroll 1
  for (int ss = 0; ss < 44; ++ss) {
    int stage = (ss & 3) + 1;
    int step = ss >> 2;
    int slot = (ss == 0) ? 0 : (3*step + (ss & 3));
    const short* xiH = xpk + (size_t)ss*XPKSTG;       // read: this stage's buffer
    short* xoH = xpk + (size_t)(ss+1)*XPKSTG;         // write: next stage's buffer

    // ---- phase A: x-frags (cached cold loads), agg MFMA, pool part 1 (VALU) ----
    const short* p0 = xiH + (((size_t)(b*16 + (w*2 + 0))*2)*64 + l)*8;
    const short* p1 = xiH + (((size_t)(b*16 + (w*2 + 1))*2)*64 + l)*8;
    bf16x8 xb0 = *(const bf16x8*)(p0);
    bf16x8 xb1 = *(const bf16x8*)(p0 + 512);
    bf16x8 xb2 = *(const bf16x8*)(p1);
    bf16x8 xb3 = *(const bf16x8*)(p1 + 512);

    // HS from LDS state
    {
      float hv = hS[t]; float hsv;
      if (stage == 1)      hsv = hv;
      else if (stage == 2) hsv = fmaf(khS[t], (1.f/3.f), hv);
      else if (stage == 3) hsv = hv - (1.f/3.f)*khS[t] + khS[512 + t];
      else                 hsv = hv + khS[t] - khS[512 + t] + khS[1024 + t];
      HS[pl*34 + o] = hsv;
    }

    // pool part 1: plp = sum_q XR[pl][2q..2q+1] . awR[q]  (overlaps MFMA below)
    float plp = 0.f;
    #pragma unroll
    for (int q = 0; q < 16; ++q) {
      float2 xv = *(const float2*)&XR[pl*36 + 2*q];
      unsigned u = awR[q];
      plp = fmaf(xv.x, __uint_as_float(u << 16), plp);
      plp = fmaf(xv.y, __uint_as_float(u & 0xffff0000u), plp);
    }

    {
      f32x4 acc0 = {0.f,0.f,0.f,0.f}, acc1 = {0.f,0.f,0.f,0.f};
      acc0 = __builtin_amdgcn_mfma_f32_16x16x32_bf16(aL2[0], xb0, acc0, 0, 0, 0);
      acc0 = __builtin_amdgcn_mfma_f32_16x16x32_bf16(aH2[0], xb0, acc0, 0, 0, 0);
      acc1 = __builtin_amdgcn_mfma_f32_16x16x32_bf16(aL2[0], xb1, acc1, 0, 0, 0);
      acc1 = __builtin_amdgcn_mfma_f32_16x16x32_bf16(aH2[0], xb1, acc1, 0, 0, 0);
      acc0 = __builtin_amdgcn_mfma_f32_16x16x32_bf16(aL2[1], xb2, acc0, 0, 0, 0);
      acc0 = __builtin_amdgcn_mfma_f32_16x16x32_bf16(aH2[1], xb2, acc0, 0, 0, 0);
      acc1 = __builtin_amdgcn_mfma_f32_16x16x32_bf16(aL2[1], xb3, acc1, 0, 0, 0);
      acc1 = __builtin_amdgcn_mfma_f32_16x16x32_bf16(aH2[1], xb3, acc1, 0, 0, 0);
      #pragma unroll
      for (int r = 0; r < 4; ++r) {
        scrA[w][lg*4+r][ll]      = acc0[r];
        scrA[w][lg*4+r][16 + ll] = acc1[r];
      }
    }
    __syncthreads();   // bar1

    // ---- B1: chain L1 (w0/1) | AG reduce (w2/3) ----
    if (w < 2) {
      bf16x8 aH = pack_hi(&HS[ll*34 + lg*8]);
      bf16x8 bH = *(const bf16x8*)(WH_l + w*512 + l*8);
      bf16x8 bL = *(const bf16x8*)(WL_l + w*512 + l*8);
      f32x4 acc = {0.f,0.f,0.f,0.f};
      acc = __builtin_amdgcn_mfma_f32_16x16x32_bf16(aH, bL, acc, 0, 0, 0);
      acc = __builtin_amdgcn_mfma_f32_16x16x32_bf16(aH, bH, acc, 0, 0, 0);
      int col = w*16 + ll;
      float bb = bF[col];
      #pragma unroll
      for (int r = 0; r < 4; ++r) X1[(lg*4+r)*34 + col] = fmaxf(acc[r] + bb, 0.f);
    } else if (w < 4) {
      int base = (t - 128)*4;
      #pragma unroll
      for (int jj = 0; jj < 4; ++jj) {
        int s = base + jj; int sp = s>>5, so = s&31;
        float v = 0.f;
        #pragma unroll
        for (int ww = 0; ww < 8; ++ww) v += scrA[ww][sp][so];
        AG[sp*36 + so] = v;
      }
    }
    __syncthreads();   // bar2

    // ---- B2: chain L2 (w0/1) | pool part 2 (all) + PL write ----
    if (w < 2) {
      bf16x8 aH = pack_hi(&X1[ll*34 + lg*8]);
      bf16x8 bH = *(const bf16x8*)(WH_l + (2+w)*512 + l*8);
      bf16x8 bL = *(const bf16x8*)(WL_l + (2+w)*512 + l*8);
      f32x4 acc = {0.f,0.f,0.f,0.f};
      acc = __builtin_amdgcn_mfma_f32_16x16x32_bf16(aH, bL, acc, 0, 0, 0);
      acc = __builtin_amdgcn_mfma_f32_16x16x32_bf16(aH, bH, acc, 0, 0, 0);
      int col = w*16 + ll;
      float bb = bF[32 + col];
      #pragma unroll
      for (int r = 0; r < 4; ++r) X2[(lg*4+r)*34 + col] = fmaxf(acc[r] + bb, 0.f);
    }
    {
      #pragma unroll
      for (int q = 0; q < 16; ++q) {
        float2 av = *(const float2*)&AG[pl*36 + 2*q];
        unsigned u = awR[16 + q];
        plp = fmaf(av.x, __uint_as_float(u << 16), plp);
        plp = fmaf(av.y, __uint_as_float(u & 0xffff0000u), plp);
      }
      PLb[pl*34 + o] = plp + abS[t];
    }
    __syncthreads();   // bar3

    // ---- D: fWout + tanh + dh -> DHT (waves 0,1) ----
    if (w < 2) {
      bf16x8 aH = pack_hi(&X2[ll*34 + lg*8]);
      float vf[2][4];
      #pragma unroll
      for (int e = 0; e < 2; ++e) {
        int T = 2*w + e;
        bf16x8 bH = *(const bf16x8*)(WH_l + (4+T)*512 + l*8);
        bf16x8 bL = *(const bf16x8*)(WL_l + (4+T)*512 + l*8);
        f32x4 acc = {0.f,0.f,0.f,0.f};
        acc = __builtin_amdgcn_mfma_f32_16x16x32_bf16(aH, bL, acc, 0, 0, 0);
        acc = __builtin_amdgcn_mfma_f32_16x16x32_bf16(aH, bH, acc, 0, 0, 0);
        int col = T*16 + ll;
        float bb = bF[64 + col];
        #pragma unroll
        for (int r = 0; r < 4; ++r) vf[e][r] = tanh_fast(acc[r] + bb);
      }
      float2 dxv[4];
      #pragma unroll
      for (int r = 0; r < 4; ++r)
        dxv[r] = *(const float2*)&dX[(size_t)slot*16384 + (size_t)(pgbase + lg*4 + r)*2];
      #pragma unroll
      for (int e = 0; e < 2; ++e) {
        int T = 2*w + e;
        float vo[4];
        #pragma unroll
        for (int r = 0; r < 4; ++r) vo[r] = __shfl_xor(vf[e][r], 1);
        if (!(l & 1)) {
          int hh = T*8 + (ll>>1);
          float4 dv;
          dv.x = vf[e][0]*dxv[0].x + vo[0]*dxv[0].y;
          dv.y = vf[e][1]*dxv[1].x + vo[1]*dxv[1].y;
          dv.z = vf[e][2]*dxv[2].x + vo[2]*dxv[2].y;
          dv.w = vf[e][3]*dxv[3].x + vo[3]*dxv[3].y;
          *(float4*)&DHT[hh*20 + lg*4] = dv;
        }
      }
    }
    __syncthreads();   // bar4

    // ---- E: vg = tanh(PL@gWout + gbout), dz partial + shfl reduce ----
    {
      bf16x8 paH = pack_hi(&PLb[ll*34 + lg*8]);
      float p[4][4] = {{0.f,0.f,0.f,0.f},{0.f,0.f,0.f,0.f},{0.f,0.f,0.f,0.f},{0.f,0.f,0.f,0.f}};
      #pragma unroll
      for (int u = 0; u < 8; ++u) {
        f32x4 acc = {0.f,0.f,0.f,0.f};
        acc = __builtin_amdgcn_mfma_f32_16x16x32_bf16(paH, gLreg[u], acc, 0, 0, 0);
        acc = __builtin_amdgcn_mfma_f32_16x16x32_bf16(paH, gHreg[u], acc, 0, 0, 0);
        int tile = w*8 + u;
        int col = tile*16 + ll, oo = col & 31;
        float gb = bGl[col];
        float4 dh4 = *(const float4*)&DHT[oo*20 + lg*4];
        int h2 = u >> 1;
        float da[4] = {dh4.x, dh4.y, dh4.z, dh4.w};
        #pragma unroll
        for (int r = 0; r < 4; ++r) {
          float tv = tanh_fast(acc[r] + gb);
          p[r][h2] = fmaf(tv, da[r], p[r][h2]);
        }
      }
      #pragma unroll
      for (int r = 0; r < 4; ++r) {
        #pragma unroll
        for (int h2 = 0; h2 < 4; ++h2) {
          float v = p[r][h2];
          v += __shfl_xor(v, 1);
          v += __shfl_xor(v, 2);
          v += __shfl_xor(v, 4);
          v += __shfl_xor(v, 8);
          if (ll == r*4 + h2) DZ[(lg*4 + r)*33 + w*4 + h2] = v;
        }
      }
    }
    __syncthreads();   // bar5

    // ---- F: RK bookkeeping in LDS state ----
    {
      float dzv = DZ[pl*33 + o];
      float dhv = DHT[o*20 + pl];
      if (stage < 4) {
        khS[(stage-1)*512 + t] = dhv;
      } else {
        float k1 = khS[t], k2 = khS[512+t], k3 = khS[1024+t];
        hS[t] = hS[t] + 0.125f*(k1 + 3.f*(k2 + k3) + dhv);
      }
      float zv = zS[t], znv;
      if (stage == 1) {
        kzS[t] = dzv;
        znv = fmaf(dzv, (1.f/3.f), zv);
      } else if (stage == 2) {
        kzS[512 + t] = dzv;
        znv = zv - (1.f/3.f)*kzS[t] + dzv;
      } else if (stage == 3) {
        kzS[1024 + t] = dzv;
        znv = zv + kzS[t] - kzS[512+t] + dzv;
      } else {
        float k1 = kzS[t], k2 = kzS[512+t], k3 = kzS[1024+t];
        znv = zv + 0.125f*(k1 + 3.f*(k2 + k3) + dzv);
        zS[t] = znv;
      }
      X1[pl*34 + o] = znv;
    }
    __syncthreads();   // bar6

    // ---- G: xrel_next; XR(LDS) + write-through packed store to renamed buf ----
    if (w < 2) {
      bf16x8 aH = pack_hi(&X1[ll*34 + lg*8]);
      bf16x8 bH = *(const bf16x8*)(WH_l + (8+w)*512 + l*8);
      bf16x8 bL = *(const bf16x8*)(WL_l + (8+w)*512 + l*8);
      f32x4 acc = {0.f,0.f,0.f,0.f};
      acc = __builtin_amdgcn_mfma_f32_16x16x32_bf16(aH, bL, acc, 0, 0, 0);
      acc = __builtin_amdgcn_mfma_f32_16x16x32_bf16(aH, bH, acc, 0, 0, 0);
      int col = w*16 + ll;
      float bb = bF[128 + col];
      int hp = ntile & 1, cch = ntile >> 1;
      unsigned short hx[4];
      #pragma unroll
      for (int r = 0; r < 4; ++r) {
        float xr = fmaxf(acc[r] + bb, 0.f);
        XR[(lg*4 + r)*36 + col] = xr;
        hx[r] = bf16h(xr);
      }
      if (ss < 43) {
        int rr0 = hp*16 + lg*4;
        size_t off0 = (((size_t)(b*16 + cch)*2 + w)*64 + ((rr0>>3)*16 + ll))*8 + (rr0&7);
        uint2 d;
        d.x = (unsigned)hx[0] | ((unsigned)hx[1] << 16);
        d.y = (unsigned)hx[2] | ((unsigned)hx[3] << 16);
        short* p = xoH + off0;
        asm volatile("global_store_dwordx2 %0, %1, off sc0 sc1" :: "v"(p), "v"(d) : "memory");
      }
    }

    if (ss < 43) batch_barrier(cnt, 32u*(ss+1));
  }

  // final z back to global for kOut
  zio[(size_t)pgbase*32 + t] = zS[t];
}

// out[b,0,n,o] = sum_h z[b,n,h]*convW[o,h] + convb[o]
__global__ void kOut(const float* __restrict__ z, const float* __restrict__ convW,
                     const float* __restrict__ convb, float* __restrict__ out) {
  int idx = blockIdx.x*256 + threadIdx.x;   // 98304
  int o = idx % 12, p = idx / 12;
  float s = convb[o];
  #pragma unroll
  for (int hh = 0; hh < 32; ++hh) s = fmaf(z[p*32 + hh], convW[o*32 + hh], s);
  out[idx] = s;
}

extern "C" void kernel_launch(void* const* d_in, const int* in_sizes, int n_in,
                              void* d_out, int out_size, void* d_ws, size_t ws_size,
                              hipStream_t stream) {
  (void)in_sizes; (void)n_in; (void)out_size; (void)ws_size;
  const float* ca     = (const float*)d_in[1];
  const float* cb     = (const float*)d_in[2];
  const float* cc2    = (const float*)d_in[3];
  const float* cd3    = (const float*)d_in[4];
  const float* Wh     = (const float*)d_in[5];
  const float* bh     = (const float*)d_in[6];
  const float* Wz     = (const float*)d_in[7];
  const float* bz     = (const float*)d_in[8];
  const float* fWin   = (const float*)d_in[9];
  const float* fbin   = (const float*)d_in[10];
  const float* fWmid  = (const float*)d_in[11];
  const float* fbmid  = (const float*)d_in[12];
  const float* fWout  = (const float*)d_in[13];
  const float* fbout  = (const float*)d_in[14];
  const float* gWin   = (const float*)d_in[15];
  const float* gbin   = (const float*)d_in[16];
  const float* gE     = (const float*)d_in[17];
  const float* gWpool = (const float*)d_in[18];
  const float* gbpool = (const float*)d_in[19];
  const float* gWout  = (const float*)d_in[20];
  const float* gbout  = (const float*)d_in[21];
  const float* convW  = (const float*)d_in[22];
  const float* convb  = (const float*)d_in[23];
  float* out = (float*)d_out;

  float* wsf  = (float*)d_ws;
  unsigned* awb = (unsigned*)wsf;            // 524288 uints
  float* wAb  = wsf + 524288;                // 16384
  float* wDX  = wAb + 16384;                 // 557056
  float* wH   = wDX + 557056;                // 262144
  float* wZ   = wH + 262144;                 // 262144
  float* wXr  = wZ + 262144;                 // 262144
  short* ApkH = (short*)(wXr + 262144);      // 262144 shorts
  short* ApkL = ApkH + 262144;               // 262144 shorts
  short* xpk  = ApkL + 262144;               // 44 * 262144 shorts (renamed buffers)
  short* GpkH = xpk + (size_t)44*XPKSTG;     // 32768
  short* GpkL = GpkH + 32768;                // 32768
  short* WpkH = GpkL + 32768;                // 5120
  short* WpkL = WpkH + 5120;                 // 5120
  unsigned* bar = (unsigned*)(WpkL + 5120);  // 1024 uints (16 batches x 64 stride)

  (void)hipMemsetAsync(bar, 0, 1024*sizeof(unsigned), stream);
  kA_softmax<<<512, 256, 0, stream>>>(gE, ApkH, ApkL);
  kAwB<<<512, 256, 0, stream>>>(gE, gWpool, gbpool, awb, wAb);
  kPackGW<<<128, 256, 0, stream>>>(gWout, GpkH, GpkL);
  kPackW<<<20, 256, 0, stream>>>(fWin, fWmid, fWout, gWin, WpkH, WpkL);
  kDX<<<2176, 256, 0, stream>>>(cb, cc2, cd3, wDX);
  kInit<<<1024, 256, 0, stream>>>(ca, Wh, bh, Wz, bz, wH, wZ);
  kXrel0<<<1024, 256, 0, stream>>>(wZ, gWin, gbin, wXr, xpk);

  kPersist<<<512, 512, 0, stream>>>(awb, wAb, wDX, wH, wZ, wXr,
                                    xpk, ApkH, ApkL, GpkH, GpkL,
                                    WpkH, WpkL, fbin, fbmid, fbout, gbin, gbout,
                                    bar);

  kOut<<<384, 256, 0, stream>>>(wZ, convW, convb, out);
}

// Round 10
// 1411.505 us; speedup vs baseline: 1.0595x; 1.0595x over previous
//
#include <hip/hip_runtime.h>
#include <math.h>

#define NPTS 8192
#define NPS  (NPTS*32)
#define XPKSTG 262144   // shorts per stage x-frag buffer (512 KB)

typedef __attribute__((ext_vector_type(8))) short bf16x8;
typedef __attribute__((ext_vector_type(4))) float f32x4;

__device__ __forceinline__ float tanh_fast(float x) {
  float e = __expf(2.0f*x);
  return 1.0f - 2.0f*__builtin_amdgcn_rcpf(e + 1.0f);
}
__device__ __forceinline__ unsigned short bf16h(float x) {
  unsigned u = __float_as_uint(x);
  return (unsigned short)((u + 0x7FFFu + ((u>>16)&1u)) >> 16);
}
__device__ __forceinline__ float bf16f(unsigned short h) {
  return __uint_as_float(((unsigned)h)<<16);
}
__device__ __forceinline__ bf16x8 pack_hi(const float* base) {
  bf16x8 H;
  #pragma unroll
  for (int jj = 0; jj < 4; ++jj) {
    float2 q = *(const float2*)(base + 2*jj);
    H[2*jj]   = (short)bf16h(q.x);
    H[2*jj+1] = (short)bf16h(q.y);
  }
  return H;
}

// ---------------- prologue kernels ----------------

__global__ void kA_softmax(const float* __restrict__ gE, short* __restrict__ ApkH,
                           short* __restrict__ ApkL) {
  __shared__ float gn[16];
  __shared__ float red[256];
  int n = blockIdx.x, t = threadIdx.x;
  if (t < 16) gn[t] = gE[n*16 + t];
  __syncthreads();
  float e0, e1;
  {
    float d = 0.f;
    #pragma unroll
    for (int dd = 0; dd < 16; ++dd) d = fmaf(gn[dd], gE[t*16 + dd], d);
    e0 = __expf(fmaxf(d, 0.f));
  }
  {
    float d = 0.f;
    #pragma unroll
    for (int dd = 0; dd < 16; ++dd) d = fmaf(gn[dd], gE[(t+256)*16 + dd], d);
    e1 = __expf(fmaxf(d, 0.f));
  }
  red[t] = e0 + e1;
  __syncthreads();
  for (int off = 128; off > 0; off >>= 1) {
    if (t < off) red[t] += red[t+off];
    __syncthreads();
  }
  float inv = __builtin_amdgcn_rcpf(red[0]);
  int nt = n >> 4;
  #pragma unroll
  for (int half = 0; half < 2; ++half) {
    int k = t + half*256;
    float v = (half ? e1 : e0) * inv;
    int c = k >> 5, g = (k>>3)&3, j = k&7;
    int l = g*16 + (n&15);
    size_t off2 = ((size_t)(nt*16 + c)*64 + l)*8 + j;
    unsigned short hb = bf16h(v);
    ApkH[off2] = (short)hb;
    ApkL[off2] = (short)bf16h(v - bf16f(hb));
  }
}

__global__ __launch_bounds__(256) void kAwB(const float* __restrict__ gE,
                      const float* __restrict__ gWpool,
                      const float* __restrict__ gbpool,
                      unsigned* __restrict__ awb, float* __restrict__ ab) {
  __shared__ float gn[16];
  int n = blockIdx.x, t = threadIdx.x;
  if (t < 16) gn[t] = gE[n*16 + t];
  __syncthreads();
  #pragma unroll
  for (int r = 0; r < 4; ++r) {
    int e = t + r*256;
    int q = e >> 5, o = e & 31;
    float s0 = 0.f, s1 = 0.f;
    #pragma unroll
    for (int d = 0; d < 16; ++d) {
      float g = gn[d];
      s0 = fmaf(g, gWpool[d*2048 + (2*q)*32 + o], s0);
      s1 = fmaf(g, gWpool[d*2048 + (2*q+1)*32 + o], s1);
    }
    awb[(size_t)n*1024 + e] = (unsigned)bf16h(s0) | ((unsigned)bf16h(s1) << 16);
  }
  if (t < 32) {
    float s = 0.f;
    #pragma unroll
    for (int d = 0; d < 16; ++d) s = fmaf(gn[d], gbpool[d*32 + t], s);
    ab[n*32 + t] = s;
  }
}

__global__ void kPackGW(const float* __restrict__ gWout, short* __restrict__ GpkH,
                        short* __restrict__ GpkL) {
  int idx = blockIdx.x*256 + threadIdx.x;   // 32768
  int j = idx & 7, l = (idx>>3)&63, tl = idx>>9;
  int col = tl*16 + (l&15);
  int k = ((l>>4)&3)*8 + j;
  float v = gWout[k*1024 + col];
  unsigned short hb = bf16h(v);
  GpkH[idx] = (short)hb;
  GpkL[idx] = (short)bf16h(v - bf16f(hb));
}

__global__ void kPackW(const float* __restrict__ fWin, const float* __restrict__ fWmid,
                       const float* __restrict__ fWout, const float* __restrict__ gWin,
                       short* __restrict__ WpkH, short* __restrict__ WpkL) {
  int idx = blockIdx.x*256 + threadIdx.x;   // 5120
  if (idx >= 5120) return;
  int j = idx & 7, l = (idx>>3)&63, T = idx>>9;
  int k = ((l>>4)&3)*8 + j;
  const float* M; int cols, tl;
  if (T < 2)      { M = fWin;  cols = 32; tl = T;   }
  else if (T < 4) { M = fWmid; cols = 32; tl = T-2; }
  else if (T < 8) { M = fWout; cols = 64; tl = T-4; }
  else            { M = gWin;  cols = 32; tl = T-8; }
  float v = M[k*cols + tl*16 + (l&15)];
  unsigned short hb = bf16h(v);
  WpkH[idx] = (short)hb;
  WpkL[idx] = (short)bf16h(v - bf16f(hb));
}

__global__ void kDX(const float* __restrict__ cb, const float* __restrict__ cc2,
                    const float* __restrict__ cd3, float* __restrict__ dX) {
  int idx = blockIdx.x*256 + threadIdx.x;       // 557056
  int slot = idx >> 14;
  int rem = idx & 16383;
  int p = rem >> 1, i = rem & 1;
  float v;
  if (slot == 0) {
    v = cb[p*22 + i];
  } else {
    int s1 = slot - 1;
    int k = s1 / 3, j = s1 - 3*k;
    float frac = (float)(j+1) * (1.0f/3.0f);
    if (j == 2) frac = 1.0f;
    int base = p*22 + k*2 + i;
    v = cb[base] + (cc2[base] + cd3[base]*frac)*frac;
  }
  dX[idx] = v;
}

__global__ void kInit(const float* __restrict__ ca, const float* __restrict__ Wh,
                      const float* __restrict__ bh, const float* __restrict__ Wz,
                      const float* __restrict__ bz, float* __restrict__ h,
                      float* __restrict__ z) {
  int idx = blockIdx.x*256 + threadIdx.x;       // 262144
  int c = idx & 31, p = idx >> 5;
  float x0 = ca[p*22 + 0], x1 = ca[p*22 + 1];
  h[idx] = fmaf(x0, Wh[c], fmaf(x1, Wh[32+c], bh[c]));
  z[idx] = fmaf(x0, Wz[c], fmaf(x1, Wz[32+c], bz[c]));
}

// initial xrel -> f32 + packed hi frags into stage-0 buffer
__global__ void kXrel0(const float* __restrict__ z, const float* __restrict__ gWin,
                       const float* __restrict__ gbin, float* __restrict__ xrel,
                       short* __restrict__ xpk0) {
  __shared__ float zl[8][32];
  int t = threadIdx.x, pl = t >> 5, o = t & 31;
  int p = blockIdx.x*8 + pl;
  zl[pl][o] = z[p*32 + o];
  __syncthreads();
  float s = gbin[o];
  #pragma unroll
  for (int i = 0; i < 32; ++i) s = fmaf(zl[pl][i], gWin[i*32 + o], s);
  float xr = fmaxf(s, 0.f);
  xrel[p*32 + o] = xr;
  int b = p >> 9, m = p & 511;
  int c = m >> 5, rr = m & 31;
  int lane = (rr>>3)*16 + (o&15);
  int tt = o >> 4;
  size_t off = (((size_t)(b*16 + c)*2 + tt)*64 + lane)*8 + (rr&7);
  xpk0[off] = (short)bf16h(xr);
}

// ---------------- persistent scan kernel ----------------

// Relaxed barrier: no acquire fence, L2 never invalidated. Cross-block x-frags
// use buffer renaming (unique buffer per stage): producers store write-through
// (sc0 sc1), consumers use NORMAL cached loads of never-before-cached lines.
__device__ __forceinline__ void batch_barrier(unsigned* __restrict__ cnt, unsigned target) {
  __syncthreads();   // drains vmcnt (write-through stores complete) per wave
  if (threadIdx.x == 0) {
    __hip_atomic_fetch_add(cnt, 1u, __ATOMIC_RELAXED, __HIP_MEMORY_SCOPE_AGENT);
    unsigned guard = 0;
    while (__hip_atomic_load(cnt, __ATOMIC_RELAXED, __HIP_MEMORY_SCOPE_AGENT) < target) {
      if (++guard > (1u<<22)) break;   // bounded: fail visibly, never hang
      __builtin_amdgcn_s_sleep(2);
    }
  }
  __syncthreads();
}

// grid 512 (b x ntile), 512 thr = 8 waves, 2 blocks/CU (all co-resident).
// NO register arrays hoisted across the stage loop (VGPR budget is 64-ish;
// hoisted arrays spill to scratch and cost ~30 MB/stage — R5-R9 lesson).
__global__ __launch_bounds__(512, 4) void kPersist(
    const unsigned* __restrict__ awb, const float* __restrict__ ab,
    const float* __restrict__ dX, const float* __restrict__ h0,
    float* __restrict__ zio, const float* __restrict__ xrel0,
    short* __restrict__ xpk,
    const short* __restrict__ ApkH, const short* __restrict__ ApkL,
    const short* __restrict__ GpkH, const short* __restrict__ GpkL,
    const short* __restrict__ WpkH, const short* __restrict__ WpkL,
    const float* __restrict__ fbin, const float* __restrict__ fbmid,
    const float* __restrict__ fbout, const float* __restrict__ gbin,
    const float* __restrict__ gbout, unsigned* __restrict__ bar)
{
  __shared__ float scrA[8][16][32];
  __shared__ float bGl[1024];
  __shared__ float HS[16*34], X1[16*34], X2[16*34], PLb[16*34];
  __shared__ float XR[16*36], AG[16*36];
  __shared__ float DHT[32*20];
  __shared__ float DZ[16*33];
  __shared__ short WH_l[5120], WL_l[5120];
  __shared__ float bF[160];
  __shared__ float abS[512];
  __shared__ float hS[512], zS[512], khS[3*512], kzS[3*512];

  int t = threadIdx.x;
  int pl = t >> 5, o = t & 31;
  int w = t >> 6, l = t & 63;
  int ll = l & 15, lg = l >> 4;
  int bid = blockIdx.x;
  int xcd = bid & 7, sub = (bid >> 3) & 3, b = bid >> 5;
  int ntile = xcd*4 + sub;
  int pgbase = b*512 + ntile*16;
  unsigned* cnt = bar + b*64;

  // ---- once: stage-invariant LDS data (no register residency) ----
  bGl[t] = gbout[t]; bGl[t+512] = gbout[t+512];
  for (int j = t; j < 5120; j += 512) { WH_l[j] = WpkH[j]; WL_l[j] = WpkL[j]; }
  if (t < 32) bF[t] = fbin[t];
  else if (t < 64) bF[t] = fbmid[t-32];
  else if (t < 128) bF[t] = fbout[t-64];
  else if (t < 160) bF[t] = gbin[t-128];
  abS[t] = ab[(size_t)(ntile*16 + pl)*32 + o];
  hS[t] = h0[(size_t)pgbase*32 + t];
  zS[t] = zio[(size_t)pgbase*32 + t];
  XR[pl*36 + o] = xrel0[(size_t)(pgbase + pl)*32 + o];
  __syncthreads();

  #pragma unroll 1
  for (int ss = 0; ss < 44; ++ss) {
    int stage = (ss & 3) + 1;
    int step = ss >> 2;
    int slot = (ss == 0) ? 0 : (3*step + (ss & 3));
    const short* xiH = xpk + (size_t)ss*XPKSTG;       // read: this stage's buffer
    short* xoH = xpk + (size_t)(ss+1)*XPKSTG;         // write: next stage's buffer

    // ---- phase 0: HS from LDS state ----
    {
      float hv = hS[t]; float hsv;
      if (stage == 1)      hsv = hv;
      else if (stage == 2) hsv = fmaf(khS[t], (1.f/3.f), hv);
      else if (stage == 3) hsv = hv - (1.f/3.f)*khS[t] + khS[512 + t];
      else                 hsv = hv + khS[t] - khS[512 + t] + khS[1024 + t];
      HS[pl*34 + o] = hsv;
    }

    // ---- phase A: agg MFMA; A-frags + x-frags loaded at use (L2-resident) ----
    {
      f32x4 acc0 = {0.f,0.f,0.f,0.f}, acc1 = {0.f,0.f,0.f,0.f};
      #pragma unroll
      for (int cc = 0; cc < 2; ++cc) {
        int c = w*2 + cc;
        size_t aoff = ((size_t)(ntile*16 + c)*64 + l)*8;
        bf16x8 aH = *(const bf16x8*)(ApkH + aoff);
        bf16x8 aL = *(const bf16x8*)(ApkL + aoff);
        const short* p0 = xiH + (((size_t)(b*16 + c)*2)*64 + l)*8;
        bf16x8 xb0 = *(const bf16x8*)(p0);
        bf16x8 xb1 = *(const bf16x8*)(p0 + 512);
        acc0 = __builtin_amdgcn_mfma_f32_16x16x32_bf16(aL, xb0, acc0, 0, 0, 0);
        acc0 = __builtin_amdgcn_mfma_f32_16x16x32_bf16(aH, xb0, acc0, 0, 0, 0);
        acc1 = __builtin_amdgcn_mfma_f32_16x16x32_bf16(aL, xb1, acc1, 0, 0, 0);
        acc1 = __builtin_amdgcn_mfma_f32_16x16x32_bf16(aH, xb1, acc1, 0, 0, 0);
      }
      #pragma unroll
      for (int r = 0; r < 4; ++r) {
        scrA[w][lg*4+r][ll]      = acc0[r];
        scrA[w][lg*4+r][16 + ll] = acc1[r];
      }
    }
    __syncthreads();   // bar1

    // ---- B1: chain L1 (w0/1) | AG reduce (w2/3) | pool part 1 (w4-7) ----
    float plp0 = 0.f, plp1 = 0.f;
    if (w < 2) {
      bf16x8 aH = pack_hi(&HS[ll*34 + lg*8]);
      bf16x8 bH = *(const bf16x8*)(WH_l + w*512 + l*8);
      bf16x8 bL = *(const bf16x8*)(WL_l + w*512 + l*8);
      f32x4 acc = {0.f,0.f,0.f,0.f};
      acc = __builtin_amdgcn_mfma_f32_16x16x32_bf16(aH, bL, acc, 0, 0, 0);
      acc = __builtin_amdgcn_mfma_f32_16x16x32_bf16(aH, bH, acc, 0, 0, 0);
      int col = w*16 + ll;
      float bb = bF[col];
      #pragma unroll
      for (int r = 0; r < 4; ++r) X1[(lg*4+r)*34 + col] = fmaxf(acc[r] + bb, 0.f);
    } else if (w < 4) {
      int base = (t - 128)*4;
      #pragma unroll
      for (int jj = 0; jj < 4; ++jj) {
        int s = base + jj; int sp = s>>5, so = s&31;
        float v = 0.f;
        #pragma unroll
        for (int ww = 0; ww < 8; ++ww) v += scrA[ww][sp][so];
        AG[sp*36 + so] = v;
      }
    } else {
      #pragma unroll
      for (int half = 0; half < 2; ++half) {
        int s = (t - 256) + half*256;
        int sp = s>>5, so = s&31;
        int nn = ntile*16 + sp;
        const unsigned* awp = awb + (size_t)nn*1024 + so;
        const float2* xr2 = (const float2*)&XR[sp*36];
        float acc = 0.f;
        #pragma unroll
        for (int q = 0; q < 16; ++q) {
          unsigned u = awp[q*32];
          float2 xv = xr2[q];
          acc = fmaf(xv.x, __uint_as_float(u << 16), acc);
          acc = fmaf(xv.y, __uint_as_float(u & 0xffff0000u), acc);
        }
        if (half == 0) plp0 = acc; else plp1 = acc;
      }
    }
    __syncthreads();   // bar2

    // ---- B2: chain L2 (w0/1) | pool part 2 + PL write (w4-7) ----
    if (w < 2) {
      bf16x8 aH = pack_hi(&X1[ll*34 + lg*8]);
      bf16x8 bH = *(const bf16x8*)(WH_l + (2+w)*512 + l*8);
      bf16x8 bL = *(const bf16x8*)(WL_l + (2+w)*512 + l*8);
      f32x4 acc = {0.f,0.f,0.f,0.f};
      acc = __builtin_amdgcn_mfma_f32_16x16x32_bf16(aH, bL, acc, 0, 0, 0);
      acc = __builtin_amdgcn_mfma_f32_16x16x32_bf16(aH, bH, acc, 0, 0, 0);
      int col = w*16 + ll;
      float bb = bF[32 + col];
      #pragma unroll
      for (int r = 0; r < 4; ++r) X2[(lg*4+r)*34 + col] = fmaxf(acc[r] + bb, 0.f);
    } else if (w >= 4) {
      #pragma unroll
      for (int half = 0; half < 2; ++half) {
        int s = (t - 256) + half*256;
        int sp = s>>5, so = s&31;
        int nn = ntile*16 + sp;
        const unsigned* awp = awb + (size_t)nn*1024 + 512 + so;
        const float2* ag2 = (const float2*)&AG[sp*36];
        float acc = (half == 0) ? plp0 : plp1;
        #pragma unroll
        for (int q = 0; q < 16; ++q) {
          unsigned u = awp[q*32];
          float2 av = ag2[q];
          acc = fmaf(av.x, __uint_as_float(u << 16), acc);
          acc = fmaf(av.y, __uint_as_float(u & 0xffff0000u), acc);
        }
        PLb[sp*34 + so] = acc + abS[s];
      }
    }
    __syncthreads();   // bar3

    // ---- D: fWout + tanh + dh -> DHT (waves 0,1) ----
    if (w < 2) {
      bf16x8 aH = pack_hi(&X2[ll*34 + lg*8]);
      float vf[2][4];
      #pragma unroll
      for (int e = 0; e < 2; ++e) {
        int T = 2*w + e;
        bf16x8 bH = *(const bf16x8*)(WH_l + (4+T)*512 + l*8);
        bf16x8 bL = *(const bf16x8*)(WL_l + (4+T)*512 + l*8);
        f32x4 acc = {0.f,0.f,0.f,0.f};
        acc = __builtin_amdgcn_mfma_f32_16x16x32_bf16(aH, bL, acc, 0, 0, 0);
        acc = __builtin_amdgcn_mfma_f32_16x16x32_bf16(aH, bH, acc, 0, 0, 0);
        int col = T*16 + ll;
        float bb = bF[64 + col];
        #pragma unroll
        for (int r = 0; r < 4; ++r) vf[e][r] = tanh_fast(acc[r] + bb);
      }
      float2 dxv[4];
      #pragma unroll
      for (int r = 0; r < 4; ++r)
        dxv[r] = *(const float2*)&dX[(size_t)slot*16384 + (size_t)(pgbase + lg*4 + r)*2];
      #pragma unroll
      for (int e = 0; e < 2; ++e) {
        int T = 2*w + e;
        float vo[4];
        #pragma unroll
        for (int r = 0; r < 4; ++r) vo[r] = __shfl_xor(vf[e][r], 1);
        if (!(l & 1)) {
          int hh = T*8 + (ll>>1);
          float4 dv;
          dv.x = vf[e][0]*dxv[0].x + vo[0]*dxv[0].y;
          dv.y = vf[e][1]*dxv[1].x + vo[1]*dxv[1].y;
          dv.z = vf[e][2]*dxv[2].x + vo[2]*dxv[2].y;
          dv.w = vf[e][3]*dxv[3].x + vo[3]*dxv[3].y;
          *(float4*)&DHT[hh*20 + lg*4] = dv;
        }
      }
    }
    __syncthreads();   // bar4

    // ---- E: vg = tanh(PL@gWout + gbout), dz partial + shfl reduce ----
    // Gpk loaded per-tile at use (128 KB shared, L2-resident on every XCD).
    {
      bf16x8 paH = pack_hi(&PLb[ll*34 + lg*8]);
      float p[4][4] = {{0.f,0.f,0.f,0.f},{0.f,0.f,0.f,0.f},{0.f,0.f,0.f,0.f},{0.f,0.f,0.f,0.f}};
      #pragma unroll
      for (int u = 0; u < 8; ++u) {
        int tile = w*8 + u;
        size_t goff = ((size_t)tile*64 + l)*8;
        bf16x8 gH = *(const bf16x8*)(GpkH + goff);
        bf16x8 gL = *(const bf16x8*)(GpkL + goff);
        f32x4 acc = {0.f,0.f,0.f,0.f};
        acc = __builtin_amdgcn_mfma_f32_16x16x32_bf16(paH, gL, acc, 0, 0, 0);
        acc = __builtin_amdgcn_mfma_f32_16x16x32_bf16(paH, gH, acc, 0, 0, 0);
        int col = tile*16 + ll, oo = col & 31;
        float gb = bGl[col];
        float4 dh4 = *(const float4*)&DHT[oo*20 + lg*4];
        int h2 = u >> 1;
        float da[4] = {dh4.x, dh4.y, dh4.z, dh4.w};
        #pragma unroll
        for (int r = 0; r < 4; ++r) {
          float tv = tanh_fast(acc[r] + gb);
          p[r][h2] = fmaf(tv, da[r], p[r][h2]);
        }
      }
      #pragma unroll
      for (int r = 0; r < 4; ++r) {
        #pragma unroll
        for (int h2 = 0; h2 < 4; ++h2) {
          float v = p[r][h2];
          v += __shfl_xor(v, 1);
          v += __shfl_xor(v, 2);
          v += __shfl_xor(v, 4);
          v += __shfl_xor(v, 8);
          if (ll == r*4 + h2) DZ[(lg*4 + r)*33 + w*4 + h2] = v;
        }
      }
    }
    __syncthreads();   // bar5

    // ---- F: RK bookkeeping in LDS state ----
    {
      float dzv = DZ[pl*33 + o];
      float dhv = DHT[o*20 + pl];
      if (stage < 4) {
        khS[(stage-1)*512 + t] = dhv;
      } else {
        float k1 = khS[t], k2 = khS[512+t], k3 = khS[1024+t];
        hS[t] = hS[t] + 0.125f*(k1 + 3.f*(k2 + k3) + dhv);
      }
      float zv = zS[t], znv;
      if (stage == 1) {
        kzS[t] = dzv;
        znv = fmaf(dzv, (1.f/3.f), zv);
      } else if (stage == 2) {
        kzS[512 + t] = dzv;
        znv = zv - (1.f/3.f)*kzS[t] + dzv;
      } else if (stage == 3) {
        kzS[1024 + t] = dzv;
        znv = zv + kzS[t] - kzS[512+t] + dzv;
      } else {
        float k1 = kzS[t], k2 = kzS[512+t], k3 = kzS[1024+t];
        znv = zv + 0.125f*(k1 + 3.f*(k2 + k3) + dzv);
        zS[t] = znv;
      }
      X1[pl*34 + o] = znv;
    }
    __syncthreads();   // bar6

    // ---- G: xrel_next; XR(LDS) + write-through packed store to renamed buf ----
    if (w < 2) {
      bf16x8 aH = pack_hi(&X1[ll*34 + lg*8]);
      bf16x8 bH = *(const bf16x8*)(WH_l + (8+w)*512 + l*8);
      bf16x8 bL = *(const bf16x8*)(WL_l + (8+w)*512 + l*8);
      f32x4 acc = {0.f,0.f,0.f,0.f};
      acc = __builtin_amdgcn_mfma_f32_16x16x32_bf16(aH, bL, acc, 0, 0, 0);
      acc = __builtin_amdgcn_mfma_f32_16x16x32_bf16(aH, bH, acc, 0, 0, 0);
      int col = w*16 + ll;
      float bb = bF[128 + col];
      int hp = ntile & 1, cch = ntile >> 1;
      unsigned short hx[4];
      #pragma unroll
      for (int r = 0; r < 4; ++r) {
        float xr = fmaxf(acc[r] + bb, 0.f);
        XR[(lg*4 + r)*36 + col] = xr;
        hx[r] = bf16h(xr);
      }
      if (ss < 43) {
        int rr0 = hp*16 + lg*4;
        size_t off0 = (((size_t)(b*16 + cch)*2 + w)*64 + ((rr0>>3)*16 + ll))*8 + (rr0&7);
        uint2 d;
        d.x = (unsigned)hx[0] | ((unsigned)hx[1] << 16);
        d.y = (unsigned)hx[2] | ((unsigned)hx[3] << 16);
        short* p = xoH + off0;
        asm volatile("global_store_dwordx2 %0, %1, off sc0 sc1" :: "v"(p), "v"(d) : "memory");
      }
    }

    if (ss < 43) batch_barrier(cnt, 32u*(ss+1));
  }

  // final z back to global for kOut
  zio[(size_t)pgbase*32 + t] = zS[t];
}

// out[b,0,n,o] = sum_h z[b,n,h]*convW[o,h] + convb[o]
__global__ void kOut(const float* __restrict__ z, const float* __restrict__ convW,
                     const float* __restrict__ convb, float* __restrict__ out) {
  int idx = blockIdx.x*256 + threadIdx.x;   // 98304
  int o = idx % 12, p = idx / 12;
  float s = convb[o];
  #pragma unroll
  for (int hh = 0; hh < 32; ++hh) s = fmaf(z[p*32 + hh], convW[o*32 + hh], s);
  out[idx] = s;
}

extern "C" void kernel_launch(void* const* d_in, const int* in_sizes, int n_in,
                              void* d_out, int out_size, void* d_ws, size_t ws_size,
                              hipStream_t stream) {
  (void)in_sizes; (void)n_in; (void)out_size; (void)ws_size;
  const float* ca     = (const float*)d_in[1];
  const float* cb     = (const float*)d_in[2];
  const float* cc2    = (const float*)d_in[3];
  const float* cd3    = (const float*)d_in[4];
  const float* Wh     = (const float*)d_in[5];
  const float* bh     = (const float*)d_in[6];
  const float* Wz     = (const float*)d_in[7];
  const float* bz     = (const float*)d_in[8];
  const float* fWin   = (const float*)d_in[9];
  const float* fbin   = (const float*)d_in[10];
  const float* fWmid  = (const float*)d_in[11];
  const float* fbmid  = (const float*)d_in[12];
  const float* fWout  = (const float*)d_in[13];
  const float* fbout  = (const float*)d_in[14];
  const float* gWin   = (const float*)d_in[15];
  const float* gbin   = (const float*)d_in[16];
  const float* gE     = (const float*)d_in[17];
  const float* gWpool = (const float*)d_in[18];
  const float* gbpool = (const float*)d_in[19];
  const float* gWout  = (const float*)d_in[20];
  const float* gbout  = (const float*)d_in[21];
  const float* convW  = (const float*)d_in[22];
  const float* convb  = (const float*)d_in[23];
  float* out = (float*)d_out;

  float* wsf  = (float*)d_ws;
  unsigned* awb = (unsigned*)wsf;            // 524288 uints
  float* wAb  = wsf + 524288;                // 16384
  float* wDX  = wAb + 16384;                 // 557056
  float* wH   = wDX + 557056;                // 262144
  float* wZ   = wH + 262144;                 // 262144
  float* wXr  = wZ + 262144;                 // 262144
  short* ApkH = (short*)(wXr + 262144);      // 262144 shorts
  short* ApkL = ApkH + 262144;               // 262144 shorts
  short* xpk  = ApkL + 262144;               // 44 * 262144 shorts (renamed buffers)
  short* GpkH = xpk + (size_t)44*XPKSTG;     // 32768
  short* GpkL = GpkH + 32768;                // 32768
  short* WpkH = GpkL + 32768;                // 5120
  short* WpkL = WpkH + 5120;                 // 5120
  unsigned* bar = (unsigned*)(WpkL + 5120);  // 1024 uints (16 batches x 64 stride)

  (void)hipMemsetAsync(bar, 0, 1024*sizeof(unsigned), stream);
  kA_softmax<<<512, 256, 0, stream>>>(gE, ApkH, ApkL);
  kAwB<<<512, 256, 0, stream>>>(gE, gWpool, gbpool, awb, wAb);
  kPackGW<<<128, 256, 0, stream>>>(gWout, GpkH, GpkL);
  kPackW<<<20, 256, 0, stream>>>(fWin, fWmid, fWout, gWin, WpkH, WpkL);
  kDX<<<2176, 256, 0, stream>>>(cb, cc2, cd3, wDX);
  kInit<<<1024, 256, 0, stream>>>(ca, Wh, bh, Wz, bz, wH, wZ);
  kXrel0<<<1024, 256, 0, stream>>>(wZ, gWin, gbin, wXr, xpk);

  kPersist<<<512, 512, 0, stream>>>(awb, wAb, wDX, wH, wZ, wXr,
                                    xpk, ApkH, ApkL, GpkH, GpkL,
                                    WpkH, WpkL, fbin, fbmid, fbout, gbin, gbout,
                                    bar);

  kOut<<<384, 256, 0, stream>>>(wZ, convW, convb, out);
}

// Round 11
// 574.250 us; speedup vs baseline: 2.6043x; 2.4580x over previous
//
#include <hip/hip_runtime.h>
#include <math.h>

#define NPTS 8192
#define NPS  (NPTS*32)

typedef __attribute__((ext_vector_type(8))) short bf16x8;
typedef __attribute__((ext_vector_type(4))) float f32x4;

__device__ __forceinline__ float tanh_fast(float x) {
  float e = __expf(2.0f*x);
  return 1.0f - 2.0f*__builtin_amdgcn_rcpf(e + 1.0f);
}
__device__ __forceinline__ unsigned short bf16h(float x) {
  unsigned u = __float_as_uint(x);
  return (unsigned short)((u + 0x7FFFu + ((u>>16)&1u)) >> 16);
}
__device__ __forceinline__ float bf16f(unsigned short h) {
  return __uint_as_float(((unsigned)h)<<16);
}
__device__ __forceinline__ bf16x8 pack_hi(const float* base) {
  bf16x8 H;
  #pragma unroll
  for (int jj = 0; jj < 4; ++jj) {
    float2 q = *(const float2*)(base + 2*jj);
    H[2*jj]   = (short)bf16h(q.x);
    H[2*jj+1] = (short)bf16h(q.y);
  }
  return H;
}

// ---------------- prologue kernels ----------------

__global__ void kA_softmax(const float* __restrict__ gE, short* __restrict__ ApkH,
                           short* __restrict__ ApkL) {
  __shared__ float gn[16];
  __shared__ float red[256];
  int n = blockIdx.x, t = threadIdx.x;
  if (t < 16) gn[t] = gE[n*16 + t];
  __syncthreads();
  float e0, e1;
  {
    float d = 0.f;
    #pragma unroll
    for (int dd = 0; dd < 16; ++dd) d = fmaf(gn[dd], gE[t*16 + dd], d);
    e0 = __expf(fmaxf(d, 0.f));
  }
  {
    float d = 0.f;
    #pragma unroll
    for (int dd = 0; dd < 16; ++dd) d = fmaf(gn[dd], gE[(t+256)*16 + dd], d);
    e1 = __expf(fmaxf(d, 0.f));
  }
  red[t] = e0 + e1;
  __syncthreads();
  for (int off = 128; off > 0; off >>= 1) {
    if (t < off) red[t] += red[t+off];
    __syncthreads();
  }
  float inv = __builtin_amdgcn_rcpf(red[0]);
  int nt = n >> 4;
  #pragma unroll
  for (int half = 0; half < 2; ++half) {
    int k = t + half*256;
    float v = (half ? e1 : e0) * inv;
    int c = k >> 5, g = (k>>3)&3, j = k&7;
    int l = g*16 + (n&15);
    size_t off2 = ((size_t)(nt*16 + c)*64 + l)*8 + j;
    unsigned short hb = bf16h(v);
    ApkH[off2] = (short)hb;
    ApkL[off2] = (short)bf16h(v - bf16f(hb));
  }
}

__global__ __launch_bounds__(256) void kAwB(const float* __restrict__ gE,
                      const float* __restrict__ gWpool,
                      const float* __restrict__ gbpool,
                      unsigned* __restrict__ awb, float* __restrict__ ab) {
  __shared__ float gn[16];
  int n = blockIdx.x, t = threadIdx.x;
  if (t < 16) gn[t] = gE[n*16 + t];
  __syncthreads();
  #pragma unroll
  for (int r = 0; r < 4; ++r) {
    int e = t + r*256;
    int q = e >> 5, o = e & 31;
    float s0 = 0.f, s1 = 0.f;
    #pragma unroll
    for (int d = 0; d < 16; ++d) {
      float g = gn[d];
      s0 = fmaf(g, gWpool[d*2048 + (2*q)*32 + o], s0);
      s1 = fmaf(g, gWpool[d*2048 + (2*q+1)*32 + o], s1);
    }
    awb[(size_t)n*1024 + e] = (unsigned)bf16h(s0) | ((unsigned)bf16h(s1) << 16);
  }
  if (t < 32) {
    float s = 0.f;
    #pragma unroll
    for (int d = 0; d < 16; ++d) s = fmaf(gn[d], gbpool[d*32 + t], s);
    ab[n*32 + t] = s;
  }
}

__global__ void kPackGW(const float* __restrict__ gWout, short* __restrict__ GpkH,
                        short* __restrict__ GpkL) {
  int idx = blockIdx.x*256 + threadIdx.x;   // 32768
  int j = idx & 7, l = (idx>>3)&63, tl = idx>>9;
  int col = tl*16 + (l&15);
  int k = ((l>>4)&3)*8 + j;
  float v = gWout[k*1024 + col];
  unsigned short hb = bf16h(v);
  GpkH[idx] = (short)hb;
  GpkL[idx] = (short)bf16h(v - bf16f(hb));
}

__global__ void kPackW(const float* __restrict__ fWin, const float* __restrict__ fWmid,
                       const float* __restrict__ fWout, const float* __restrict__ gWin,
                       short* __restrict__ WpkH, short* __restrict__ WpkL) {
  int idx = blockIdx.x*256 + threadIdx.x;   // 5120
  if (idx >= 5120) return;
  int j = idx & 7, l = (idx>>3)&63, T = idx>>9;
  int k = ((l>>4)&3)*8 + j;
  const float* M; int cols, tl;
  if (T < 2)      { M = fWin;  cols = 32; tl = T;   }
  else if (T < 4) { M = fWmid; cols = 32; tl = T-2; }
  else if (T < 8) { M = fWout; cols = 64; tl = T-4; }
  else            { M = gWin;  cols = 32; tl = T-8; }
  float v = M[k*cols + tl*16 + (l&15)];
  unsigned short hb = bf16h(v);
  WpkH[idx] = (short)hb;
  WpkL[idx] = (short)bf16h(v - bf16f(hb));
}

__global__ void kDX(const float* __restrict__ cb, const float* __restrict__ cc2,
                    const float* __restrict__ cd3, float* __restrict__ dX) {
  int idx = blockIdx.x*256 + threadIdx.x;       // 557056
  int slot = idx >> 14;
  int rem = idx & 16383;
  int p = rem >> 1, i = rem & 1;
  float v;
  if (slot == 0) {
    v = cb[p*22 + i];
  } else {
    int s1 = slot - 1;
    int k = s1 / 3, j = s1 - 3*k;
    float frac = (float)(j+1) * (1.0f/3.0f);
    if (j == 2) frac = 1.0f;
    int base = p*22 + k*2 + i;
    v = cb[base] + (cc2[base] + cd3[base]*frac)*frac;
  }
  dX[idx] = v;
}

__global__ void kInit(const float* __restrict__ ca, const float* __restrict__ Wh,
                      const float* __restrict__ bh, const float* __restrict__ Wz,
                      const float* __restrict__ bz, float* __restrict__ h,
                      float* __restrict__ z) {
  int idx = blockIdx.x*256 + threadIdx.x;       // 262144
  int c = idx & 31, p = idx >> 5;
  float x0 = ca[p*22 + 0], x1 = ca[p*22 + 1];
  h[idx] = fmaf(x0, Wh[c], fmaf(x1, Wh[32+c], bh[c]));
  z[idx] = fmaf(x0, Wz[c], fmaf(x1, Wz[32+c], bz[c]));
}

__global__ void kXrel0(const float* __restrict__ z, const float* __restrict__ gWin,
                       const float* __restrict__ gbin, float* __restrict__ xrel,
                       short* __restrict__ xpkH) {
  __shared__ float zl[8][32];
  int t = threadIdx.x, pl = t >> 5, o = t & 31;
  int p = blockIdx.x*8 + pl;
  zl[pl][o] = z[p*32 + o];
  __syncthreads();
  float s = gbin[o];
  #pragma unroll
  for (int i = 0; i < 32; ++i) s = fmaf(zl[pl][i], gWin[i*32 + o], s);
  float xr = fmaxf(s, 0.f);
  xrel[p*32 + o] = xr;
  int b = p >> 9, m = p & 511;
  int c = m >> 5, rr = m & 31;
  int lane = (rr>>3)*16 + (o&15);
  int tt = o >> 4;
  size_t off = (((size_t)(b*16 + c)*2 + tt)*64 + lane)*8 + (rr&7);
  xpkH[off] = (short)bf16h(xr);
}

// ---------------- fused per-stage kernel (multi-launch, 4 barriers) ----------------
// 512 thr = 8 waves, 16 points, grid 512 (b x ntile, XCD-swizzled).
// Wave roles in phase B: w0/w1 full f-chain in-wave (duplicated, no barrier);
// w4-7 AG-reduce (own rows) + pooled einsum in-wave; w2/w3 idle.
__global__ __launch_bounds__(512, 4) void kBF(
    const unsigned* __restrict__ awb, const float* __restrict__ ab,
    const float* __restrict__ dX, float* __restrict__ h, float* __restrict__ z,
    float* __restrict__ kh, float* __restrict__ kz,
    float* __restrict__ xrel,
    const short* __restrict__ ApkH, const short* __restrict__ ApkL,
    const short* __restrict__ xpkH, short* __restrict__ xpkHo,
    const short* __restrict__ GpkH, const short* __restrict__ GpkL,
    const short* __restrict__ WpkH, const short* __restrict__ WpkL,
    const float* __restrict__ fbin, const float* __restrict__ fbmid,
    const float* __restrict__ fbout, const float* __restrict__ gbin,
    const float* __restrict__ gbout, int stage, int slot)
{
  __shared__ float scrA[8][16][32];
  __shared__ float bGl[1024];
  __shared__ float HS[16*34], X1[16*34], X2[16*34], PLb[16*34];
  __shared__ float XR[16*36], AG[16*36];
  __shared__ float DHT[32*20];
  __shared__ float DZ[16*33];

  int t = threadIdx.x;
  int pl = t >> 5, o = t & 31;
  int w = t >> 6, l = t & 63;
  int ll = l & 15, lg = l >> 4;
  int bid = blockIdx.x;
  int xcd = bid & 7, sub = (bid >> 3) & 3, b = bid >> 5;
  int ntile = xcd*4 + sub;
  int pgbase = b*512 + ntile*16;
  int pg = pgbase + pl;

  // ---- phase 0: prefetch gWout-hi frags; stage bGl, XR, HS ----
  bf16x8 gHreg[8];
  #pragma unroll
  for (int u = 0; u < 8; ++u)
    gHreg[u] = *(const bf16x8*)(GpkH + ((size_t)(w*8 + u)*64 + l)*8);

  bGl[t] = gbout[t]; bGl[t+512] = gbout[t+512];
  XR[pl*36 + o] = xrel[pg*32 + o];
  {
    float hv = h[pg*32 + o]; float hsv;
    if (stage == 1)      hsv = hv;
    else if (stage == 2) hsv = fmaf(kh[pg*32+o], (1.f/3.f), hv);
    else if (stage == 3) hsv = hv - (1.f/3.f)*kh[pg*32+o] + kh[NPS + pg*32+o];
    else                 hsv = hv + kh[pg*32+o] - kh[NPS + pg*32+o] + kh[2*NPS + pg*32+o];
    HS[pl*34 + o] = hsv;
  }

  // ---- phase A: agg MFMA (A hi+lo, x hi only) ----
  {
    f32x4 acc0 = {0.f,0.f,0.f,0.f}, acc1 = {0.f,0.f,0.f,0.f};
    #pragma unroll
    for (int cc = 0; cc < 2; ++cc) {
      int c = w*2 + cc;
      size_t aoff = ((size_t)(ntile*16 + c)*64 + l)*8;
      bf16x8 aH = *(const bf16x8*)(ApkH + aoff);
      bf16x8 aL = *(const bf16x8*)(ApkL + aoff);
      size_t boff0 = (((size_t)(b*16 + c)*2 + 0)*64 + l)*8;
      bf16x8 bH0 = *(const bf16x8*)(xpkH + boff0);
      bf16x8 bH1 = *(const bf16x8*)(xpkH + boff0 + 512);
      acc0 = __builtin_amdgcn_mfma_f32_16x16x32_bf16(aL, bH0, acc0, 0, 0, 0);
      acc0 = __builtin_amdgcn_mfma_f32_16x16x32_bf16(aH, bH0, acc0, 0, 0, 0);
      acc1 = __builtin_amdgcn_mfma_f32_16x16x32_bf16(aL, bH1, acc1, 0, 0, 0);
      acc1 = __builtin_amdgcn_mfma_f32_16x16x32_bf16(aH, bH1, acc1, 0, 0, 0);
    }
    #pragma unroll
    for (int r = 0; r < 4; ++r) {
      scrA[w][lg*4+r][ll]      = acc0[r];
      scrA[w][lg*4+r][16 + ll] = acc1[r];
    }
  }
  __syncthreads();   // bar1

  // ---- phase B: chain (w0/w1, in-wave) | AG+pool (w4-7, in-wave) ----
  if (w < 2) {
    // L1: all 32 cols (duplicated on both waves; same-value LDS writes benign)
    {
      bf16x8 aH = pack_hi(&HS[ll*34 + lg*8]);
      #pragma unroll
      for (int tile = 0; tile < 2; ++tile) {
        bf16x8 bH = *(const bf16x8*)(WpkH + (size_t)tile*512 + l*8);
        bf16x8 bL = *(const bf16x8*)(WpkL + (size_t)tile*512 + l*8);
        f32x4 acc = {0.f,0.f,0.f,0.f};
        acc = __builtin_amdgcn_mfma_f32_16x16x32_bf16(aH, bL, acc, 0, 0, 0);
        acc = __builtin_amdgcn_mfma_f32_16x16x32_bf16(aH, bH, acc, 0, 0, 0);
        int col = tile*16 + ll;
        float bb = fbin[col];
        #pragma unroll
        for (int r = 0; r < 4; ++r) X1[(lg*4+r)*34 + col] = fmaxf(acc[r] + bb, 0.f);
      }
    }
    // L2 (in-wave dep on X1)
    {
      bf16x8 aH = pack_hi(&X1[ll*34 + lg*8]);
      #pragma unroll
      for (int tile = 0; tile < 2; ++tile) {
        bf16x8 bH = *(const bf16x8*)(WpkH + (size_t)(2+tile)*512 + l*8);
        bf16x8 bL = *(const bf16x8*)(WpkL + (size_t)(2+tile)*512 + l*8);
        f32x4 acc = {0.f,0.f,0.f,0.f};
        acc = __builtin_amdgcn_mfma_f32_16x16x32_bf16(aH, bL, acc, 0, 0, 0);
        acc = __builtin_amdgcn_mfma_f32_16x16x32_bf16(aH, bH, acc, 0, 0, 0);
        int col = tile*16 + ll;
        float bb = fbmid[col];
        #pragma unroll
        for (int r = 0; r < 4; ++r) X2[(lg*4+r)*34 + col] = fmaxf(acc[r] + bb, 0.f);
      }
    }
    // D: fWout + tanh + dh (each wave its own T pair)
    {
      bf16x8 aH = pack_hi(&X2[ll*34 + lg*8]);
      float vf[2][4];
      #pragma unroll
      for (int e = 0; e < 2; ++e) {
        int T = 2*w + e;
        bf16x8 bH = *(const bf16x8*)(WpkH + (size_t)(4+T)*512 + l*8);
        bf16x8 bL = *(const bf16x8*)(WpkL + (size_t)(4+T)*512 + l*8);
        f32x4 acc = {0.f,0.f,0.f,0.f};
        acc = __builtin_amdgcn_mfma_f32_16x16x32_bf16(aH, bL, acc, 0, 0, 0);
        acc = __builtin_amdgcn_mfma_f32_16x16x32_bf16(aH, bH, acc, 0, 0, 0);
        int col = T*16 + ll;
        float bb = fbout[col];
        #pragma unroll
        for (int r = 0; r < 4; ++r) vf[e][r] = tanh_fast(acc[r] + bb);
      }
      float2 dxv[4];
      #pragma unroll
      for (int r = 0; r < 4; ++r)
        dxv[r] = *(const float2*)&dX[(size_t)slot*16384 + (size_t)(pgbase + lg*4 + r)*2];
      #pragma unroll
      for (int e = 0; e < 2; ++e) {
        int T = 2*w + e;
        float vo[4];
        #pragma unroll
        for (int r = 0; r < 4; ++r) vo[r] = __shfl_xor(vf[e][r], 1);
        if (!(l & 1)) {
          int hh = T*8 + (ll>>1);
          float4 dv;
          dv.x = vf[e][0]*dxv[0].x + vo[0]*dxv[0].y;
          dv.y = vf[e][1]*dxv[1].x + vo[1]*dxv[1].y;
          dv.z = vf[e][2]*dxv[2].x + vo[2]*dxv[2].y;
          dv.w = vf[e][3]*dxv[3].x + vo[3]*dxv[3].y;
          *(float4*)&DHT[hh*20 + lg*4] = dv;
        }
      }
    }
  } else if (w >= 4) {
    // AG reduce for own rows (in-wave), then pooled einsum
    #pragma unroll
    for (int half = 0; half < 2; ++half) {
      int s = (t - 256) + half*256;
      int sp = s>>5, so = s&31;
      float v = 0.f;
      #pragma unroll
      for (int ww = 0; ww < 8; ++ww) v += scrA[ww][sp][so];
      AG[sp*36 + so] = v;
    }
    #pragma unroll
    for (int half = 0; half < 2; ++half) {
      int s = (t - 256) + half*256;
      int sp = s>>5, so = s&31;
      int nn = ntile*16 + sp;
      const unsigned* awp = awb + (size_t)nn*1024 + so;
      const float2* xr2 = (const float2*)&XR[sp*36];
      const float2* ag2 = (const float2*)&AG[sp*36];
      float acc = 0.f;
      #pragma unroll
      for (int q = 0; q < 16; ++q) {
        unsigned u = awp[q*32];
        float2 xv = xr2[q];
        acc = fmaf(xv.x, __uint_as_float(u << 16), acc);
        acc = fmaf(xv.y, __uint_as_float(u & 0xffff0000u), acc);
      }
      #pragma unroll
      for (int q = 0; q < 16; ++q) {
        unsigned u = awp[512 + q*32];
        float2 av = ag2[q];
        acc = fmaf(av.x, __uint_as_float(u << 16), acc);
        acc = fmaf(av.y, __uint_as_float(u & 0xffff0000u), acc);
      }
      PLb[sp*34 + so] = acc + ab[nn*32 + so];
    }
  }
  __syncthreads();   // bar2

  // ---- phase E: vg = tanh(PL@gWout + gbout), dz partial + shfl reduce ----
  {
    bf16x8 paH = pack_hi(&PLb[ll*34 + lg*8]);
    bf16x8 gLreg[8];
    #pragma unroll
    for (int u = 0; u < 8; ++u)
      gLreg[u] = *(const bf16x8*)(GpkL + ((size_t)(w*8 + u)*64 + l)*8);
    float p[4][4] = {{0.f,0.f,0.f,0.f},{0.f,0.f,0.f,0.f},{0.f,0.f,0.f,0.f},{0.f,0.f,0.f,0.f}};
    #pragma unroll
    for (int u = 0; u < 8; ++u) {
      f32x4 acc = {0.f,0.f,0.f,0.f};
      acc = __builtin_amdgcn_mfma_f32_16x16x32_bf16(paH, gLreg[u], acc, 0, 0, 0);
      acc = __builtin_amdgcn_mfma_f32_16x16x32_bf16(paH, gHreg[u], acc, 0, 0, 0);
      int tile = w*8 + u;
      int col = tile*16 + ll, oo = col & 31;
      float gb = bGl[col];
      float4 dh4 = *(const float4*)&DHT[oo*20 + lg*4];
      int h2 = u >> 1;
      float da[4] = {dh4.x, dh4.y, dh4.z, dh4.w};
      #pragma unroll
      for (int r = 0; r < 4; ++r) {
        float tv = tanh_fast(acc[r] + gb);
        p[r][h2] = fmaf(tv, da[r], p[r][h2]);
      }
    }
    #pragma unroll
    for (int r = 0; r < 4; ++r) {
      #pragma unroll
      for (int h2 = 0; h2 < 4; ++h2) {
        float v = p[r][h2];
        v += __shfl_xor(v, 1);
        v += __shfl_xor(v, 2);
        v += __shfl_xor(v, 4);
        v += __shfl_xor(v, 8);
        if (ll == r*4 + h2) DZ[(lg*4 + r)*33 + w*4 + h2] = v;
      }
    }
  }
  __syncthreads();   // bar3

  // ---- phase F: RK bookkeeping (h & z), z_next -> X1 ----
  {
    float dzv = DZ[pl*33 + o];
    float dhv = DHT[o*20 + pl];
    if (stage < 4) {
      kh[(size_t)(stage-1)*NPS + pg*32 + o] = dhv;
    } else {
      float hv = h[pg*32+o];
      float k1 = kh[pg*32+o], k2 = kh[NPS+pg*32+o], k3 = kh[2*NPS+pg*32+o];
      h[pg*32+o] = hv + 0.125f*(k1 + 3.f*(k2 + k3) + dhv);
    }
    float zv = z[pg*32 + o];
    float znv;
    if (stage == 1) {
      kz[pg*32+o] = dzv;
      znv = fmaf(dzv, (1.f/3.f), zv);
    } else if (stage == 2) {
      kz[NPS + pg*32+o] = dzv;
      znv = zv - (1.f/3.f)*kz[pg*32+o] + dzv;
    } else if (stage == 3) {
      kz[2*NPS + pg*32+o] = dzv;
      znv = zv + kz[pg*32+o] - kz[NPS+pg*32+o] + dzv;
    } else {
      float k1 = kz[pg*32+o], k2 = kz[NPS+pg*32+o], k3 = kz[2*NPS+pg*32+o];
      znv = zv + 0.125f*(k1 + 3.f*(k2 + k3) + dzv);
      z[pg*32+o] = znv;
    }
    X1[pl*34 + o] = znv;   // reuse X1 as z_next
  }
  __syncthreads();   // bar4

  // ---- phase G: xrel_next = relu(z_next@gWin+gbin); store f32 + packed hi ----
  if (w < 2) {
    bf16x8 aH = pack_hi(&X1[ll*34 + lg*8]);
    bf16x8 bH = *(const bf16x8*)(WpkH + (size_t)(8+w)*512 + l*8);
    bf16x8 bL = *(const bf16x8*)(WpkL + (size_t)(8+w)*512 + l*8);
    f32x4 acc = {0.f,0.f,0.f,0.f};
    acc = __builtin_amdgcn_mfma_f32_16x16x32_bf16(aH, bL, acc, 0, 0, 0);
    acc = __builtin_amdgcn_mfma_f32_16x16x32_bf16(aH, bH, acc, 0, 0, 0);
    int col = w*16 + ll;
    float bb = gbin[col];
    int hp = ntile & 1, cch = ntile >> 1;
    #pragma unroll
    for (int r = 0; r < 4; ++r) {
      float xr = fmaxf(acc[r] + bb, 0.f);
      int row = lg*4 + r;
      xrel[(size_t)(pgbase + row)*32 + col] = xr;
      int rr = hp*16 + row;
      size_t off = (((size_t)(b*16 + cch)*2 + w)*64 + ((rr>>3)*16 + ll))*8 + (rr&7);
      xpkHo[off] = (short)bf16h(xr);
    }
  }
}

// out[b,0,n,o] = sum_h z[b,n,h]*convW[o,h] + convb[o]
__global__ void kOut(const float* __restrict__ z, const float* __restrict__ convW,
                     const float* __restrict__ convb, float* __restrict__ out) {
  int idx = blockIdx.x*256 + threadIdx.x;   // 98304
  int o = idx % 12, p = idx / 12;
  float s = convb[o];
  #pragma unroll
  for (int hh = 0; hh < 32; ++hh) s = fmaf(z[p*32 + hh], convW[o*32 + hh], s);
  out[idx] = s;
}

extern "C" void kernel_launch(void* const* d_in, const int* in_sizes, int n_in,
                              void* d_out, int out_size, void* d_ws, size_t ws_size,
                              hipStream_t stream) {
  (void)in_sizes; (void)n_in; (void)out_size; (void)ws_size;
  const float* ca     = (const float*)d_in[1];
  const float* cb     = (const float*)d_in[2];
  const float* cc2    = (const float*)d_in[3];
  const float* cd3    = (const float*)d_in[4];
  const float* Wh     = (const float*)d_in[5];
  const float* bh     = (const float*)d_in[6];
  const float* Wz     = (const float*)d_in[7];
  const float* bz     = (const float*)d_in[8];
  const float* fWin   = (const float*)d_in[9];
  const float* fbin   = (const float*)d_in[10];
  const float* fWmid  = (const float*)d_in[11];
  const float* fbmid  = (const float*)d_in[12];
  const float* fWout  = (const float*)d_in[13];
  const float* fbout  = (const float*)d_in[14];
  const float* gWin   = (const float*)d_in[15];
  const float* gbin   = (const float*)d_in[16];
  const float* gE     = (const float*)d_in[17];
  const float* gWpool = (const float*)d_in[18];
  const float* gbpool = (const float*)d_in[19];
  const float* gWout  = (const float*)d_in[20];
  const float* gbout  = (const float*)d_in[21];
  const float* convW  = (const float*)d_in[22];
  const float* convb  = (const float*)d_in[23];
  float* out = (float*)d_out;

  float* wsf  = (float*)d_ws;
  unsigned* awb = (unsigned*)wsf;            // 524288 uints
  float* wAb  = wsf + 524288;                // 16384
  float* wDX  = wAb + 16384;                 // 557056
  float* wH   = wDX + 557056;                // 262144
  float* wZ   = wH + 262144;                 // 262144
  float* wKh  = wZ + 262144;                 // 786432
  float* wKz  = wKh + 786432;                // 786432
  float* wXr  = wKz + 786432;                // 262144
  short* ApkH = (short*)(wXr + 262144);      // 262144 shorts each below
  short* ApkL = ApkH + 262144;
  short* xp0H = ApkL + 262144;
  short* xp1H = xp0H + 262144;
  short* GpkH = xp1H + 262144;               // 32768
  short* GpkL = GpkH + 32768;                // 32768
  short* WpkH = GpkL + 32768;                // 5120
  short* WpkL = WpkH + 5120;                 // 5120

  kA_softmax<<<512, 256, 0, stream>>>(gE, ApkH, ApkL);
  kAwB<<<512, 256, 0, stream>>>(gE, gWpool, gbpool, awb, wAb);
  kPackGW<<<128, 256, 0, stream>>>(gWout, GpkH, GpkL);
  kPackW<<<20, 256, 0, stream>>>(fWin, fWmid, fWout, gWin, WpkH, WpkL);
  kDX<<<2176, 256, 0, stream>>>(cb, cc2, cd3, wDX);
  kInit<<<1024, 256, 0, stream>>>(ca, Wh, bh, Wz, bz, wH, wZ);
  kXrel0<<<1024, 256, 0, stream>>>(wZ, gWin, gbin, wXr, xp0H);

  for (int ss = 0; ss < 44; ++ss) {
    int stage = (ss & 3) + 1;
    int step = ss >> 2;
    int slot = (ss == 0) ? 0 : (3*step + (ss & 3));
    const short* xiH = (ss & 1) ? xp1H : xp0H;
    short* xoH = (ss & 1) ? xp0H : xp1H;
    kBF<<<512, 512, 0, stream>>>(awb, wAb, wDX, wH, wZ, wKh, wKz, wXr,
                                 ApkH, ApkL, xiH, xoH, GpkH, GpkL,
                                 WpkH, WpkL, fbin, fbmid, fbout, gbin, gbout,
                                 stage, slot);
  }
  kOut<<<384, 256, 0, stream>>>(wZ, convW, convb, out);
}

// Round 12
// 566.193 us; speedup vs baseline: 2.6414x; 1.0142x over previous
//
#include <hip/hip_runtime.h>
#include <math.h>

#define NPTS 8192
#define NPS  (NPTS*32)

typedef __attribute__((ext_vector_type(8))) short bf16x8;
typedef __attribute__((ext_vector_type(4))) float f32x4;

__device__ __forceinline__ float tanh_fast(float x) {
  float e = __expf(2.0f*x);
  return 1.0f - 2.0f*__builtin_amdgcn_rcpf(e + 1.0f);
}
__device__ __forceinline__ unsigned short bf16h(float x) {
  unsigned u = __float_as_uint(x);
  return (unsigned short)((u + 0x7FFFu + ((u>>16)&1u)) >> 16);
}
__device__ __forceinline__ float bf16f(unsigned short h) {
  return __uint_as_float(((unsigned)h)<<16);
}
__device__ __forceinline__ bf16x8 pack_hi(const float* base) {
  bf16x8 H;
  #pragma unroll
  for (int jj = 0; jj < 4; ++jj) {
    float2 q = *(const float2*)(base + 2*jj);
    H[2*jj]   = (short)bf16h(q.x);
    H[2*jj+1] = (short)bf16h(q.y);
  }
  return H;
}

// ---------------- prologue kernels ----------------

__global__ void kA_softmax(const float* __restrict__ gE, short* __restrict__ ApkH,
                           short* __restrict__ ApkL) {
  __shared__ float gn[16];
  __shared__ float red[256];
  int n = blockIdx.x, t = threadIdx.x;
  if (t < 16) gn[t] = gE[n*16 + t];
  __syncthreads();
  float e0, e1;
  {
    float d = 0.f;
    #pragma unroll
    for (int dd = 0; dd < 16; ++dd) d = fmaf(gn[dd], gE[t*16 + dd], d);
    e0 = __expf(fmaxf(d, 0.f));
  }
  {
    float d = 0.f;
    #pragma unroll
    for (int dd = 0; dd < 16; ++dd) d = fmaf(gn[dd], gE[(t+256)*16 + dd], d);
    e1 = __expf(fmaxf(d, 0.f));
  }
  red[t] = e0 + e1;
  __syncthreads();
  for (int off = 128; off > 0; off >>= 1) {
    if (t < off) red[t] += red[t+off];
    __syncthreads();
  }
  float inv = __builtin_amdgcn_rcpf(red[0]);
  int nt = n >> 4;
  #pragma unroll
  for (int half = 0; half < 2; ++half) {
    int k = t + half*256;
    float v = (half ? e1 : e0) * inv;
    int c = k >> 5, g = (k>>3)&3, j = k&7;
    int l = g*16 + (n&15);
    size_t off2 = ((size_t)(nt*16 + c)*64 + l)*8 + j;
    unsigned short hb = bf16h(v);
    ApkH[off2] = (short)hb;
    ApkL[off2] = (short)bf16h(v - bf16f(hb));
  }
}

__global__ __launch_bounds__(256) void kAwB(const float* __restrict__ gE,
                      const float* __restrict__ gWpool,
                      const float* __restrict__ gbpool,
                      unsigned* __restrict__ awb, float* __restrict__ ab) {
  __shared__ float gn[16];
  int n = blockIdx.x, t = threadIdx.x;
  if (t < 16) gn[t] = gE[n*16 + t];
  __syncthreads();
  #pragma unroll
  for (int r = 0; r < 4; ++r) {
    int e = t + r*256;
    int q = e >> 5, o = e & 31;
    float s0 = 0.f, s1 = 0.f;
    #pragma unroll
    for (int d = 0; d < 16; ++d) {
      float g = gn[d];
      s0 = fmaf(g, gWpool[d*2048 + (2*q)*32 + o], s0);
      s1 = fmaf(g, gWpool[d*2048 + (2*q+1)*32 + o], s1);
    }
    awb[(size_t)n*1024 + e] = (unsigned)bf16h(s0) | ((unsigned)bf16h(s1) << 16);
  }
  if (t < 32) {
    float s = 0.f;
    #pragma unroll
    for (int d = 0; d < 16; ++d) s = fmaf(gn[d], gbpool[d*32 + t], s);
    ab[n*32 + t] = s;
  }
}

// fused: dX table (bids 0..2175) | gWout pack (2176..2303) | small-W pack (2304..2323)
__global__ void kPrep(const float* __restrict__ cb, const float* __restrict__ cc2,
                      const float* __restrict__ cd3, float* __restrict__ dX,
                      const float* __restrict__ gWout, short* __restrict__ GpkH,
                      short* __restrict__ GpkL,
                      const float* __restrict__ fWin, const float* __restrict__ fWmid,
                      const float* __restrict__ fWout, const float* __restrict__ gWin,
                      short* __restrict__ WpkH, short* __restrict__ WpkL) {
  int bid = blockIdx.x, t = threadIdx.x;
  if (bid < 2176) {
    int idx = bid*256 + t;
    int slot = idx >> 14;
    int rem = idx & 16383;
    int p = rem >> 1, i = rem & 1;
    float v;
    if (slot == 0) {
      v = cb[p*22 + i];
    } else {
      int s1 = slot - 1;
      int k = s1 / 3, j = s1 - 3*k;
      float frac = (float)(j+1) * (1.0f/3.0f);
      if (j == 2) frac = 1.0f;
      int base = p*22 + k*2 + i;
      v = cb[base] + (cc2[base] + cd3[base]*frac)*frac;
    }
    dX[idx] = v;
  } else if (bid < 2304) {
    int idx = (bid-2176)*256 + t;   // 32768
    int j = idx & 7, l = (idx>>3)&63, tl = idx>>9;
    int col = tl*16 + (l&15);
    int k = ((l>>4)&3)*8 + j;
    float v = gWout[k*1024 + col];
    unsigned short hb = bf16h(v);
    GpkH[idx] = (short)hb;
    GpkL[idx] = (short)bf16h(v - bf16f(hb));
  } else {
    int idx = (bid-2304)*256 + t;   // 5120
    if (idx >= 5120) return;
    int j = idx & 7, l = (idx>>3)&63, T = idx>>9;
    int k = ((l>>4)&3)*8 + j;
    const float* M; int cols, tl;
    if (T < 2)      { M = fWin;  cols = 32; tl = T;   }
    else if (T < 4) { M = fWmid; cols = 32; tl = T-2; }
    else if (T < 8) { M = fWout; cols = 64; tl = T-4; }
    else            { M = gWin;  cols = 32; tl = T-8; }
    float v = M[k*cols + tl*16 + (l&15)];
    unsigned short hb = bf16h(v);
    WpkH[idx] = (short)hb;
    WpkL[idx] = (short)bf16h(v - bf16f(hb));
  }
}

__global__ void kInit(const float* __restrict__ ca, const float* __restrict__ Wh,
                      const float* __restrict__ bh, const float* __restrict__ Wz,
                      const float* __restrict__ bz, float* __restrict__ h,
                      float* __restrict__ z) {
  int idx = blockIdx.x*256 + threadIdx.x;       // 262144
  int c = idx & 31, p = idx >> 5;
  float x0 = ca[p*22 + 0], x1 = ca[p*22 + 1];
  h[idx] = fmaf(x0, Wh[c], fmaf(x1, Wh[32+c], bh[c]));
  z[idx] = fmaf(x0, Wz[c], fmaf(x1, Wz[32+c], bz[c]));
}

__global__ void kXrel0(const float* __restrict__ z, const float* __restrict__ gWin,
                       const float* __restrict__ gbin, float* __restrict__ xrel,
                       short* __restrict__ xpkH) {
  __shared__ float zl[8][32];
  int t = threadIdx.x, pl = t >> 5, o = t & 31;
  int p = blockIdx.x*8 + pl;
  zl[pl][o] = z[p*32 + o];
  __syncthreads();
  float s = gbin[o];
  #pragma unroll
  for (int i = 0; i < 32; ++i) s = fmaf(zl[pl][i], gWin[i*32 + o], s);
  float xr = fmaxf(s, 0.f);
  xrel[p*32 + o] = xr;
  int b = p >> 9, m = p & 511;
  int c = m >> 5, rr = m & 31;
  int lane = (rr>>3)*16 + (o&15);
  int tt = o >> 4;
  size_t off = (((size_t)(b*16 + c)*2 + tt)*64 + lane)*8 + (rr&7);
  xpkH[off] = (short)bf16h(xr);
}

// ---------------- fused per-stage kernel (3 barriers) ----------------
// 512 thr = 8 waves, 16 points, grid 512 (b x ntile, XCD-swizzled).
// Phases: A(agg MFMA) | bar | B(chain in-wave w0/1, AG+pool in-wave w4-7) | bar |
// E(gWout+dz)+F(RK, own-wave DZ layout, no barrier) | bar | G(xrel_next) or conv-out.
__global__ __launch_bounds__(512, 4) void kBF(
    const unsigned* __restrict__ awb, const float* __restrict__ ab,
    const float* __restrict__ dX, float* __restrict__ h, float* __restrict__ z,
    float* __restrict__ kh, float* __restrict__ kz,
    float* __restrict__ xrel,
    const short* __restrict__ ApkH, const short* __restrict__ ApkL,
    const short* __restrict__ xpkH, short* __restrict__ xpkHo,
    const short* __restrict__ GpkH, const short* __restrict__ GpkL,
    const short* __restrict__ WpkH, const short* __restrict__ WpkL,
    const float* __restrict__ fbin, const float* __restrict__ fbmid,
    const float* __restrict__ fbout, const float* __restrict__ gbin,
    const float* __restrict__ gbout,
    const float* __restrict__ convW, const float* __restrict__ convb,
    float* __restrict__ out, int stage, int slot, int isLast)
{
  __shared__ float scrA[8][16][32];
  __shared__ float bGl[1024];
  __shared__ float HS[16*34], X1[16*34], X2[16*34], PLb[16*34];
  __shared__ float XR[16*36], AG[16*36];
  __shared__ float DHT[32*20];
  __shared__ float DZ[16*33];

  int t = threadIdx.x;
  int pl = t >> 5, o = t & 31;
  int w = t >> 6, l = t & 63;
  int ll = l & 15, lg = l >> 4;
  int bid = blockIdx.x;
  int xcd = bid & 7, sub = (bid >> 3) & 3, b = bid >> 5;
  int ntile = xcd*4 + sub;
  int pgbase = b*512 + ntile*16;
  int pg = pgbase + pl;

  // ---- phase 0: prefetch gWout-hi frags; stage bGl, XR, HS ----
  bf16x8 gHreg[8];
  #pragma unroll
  for (int u = 0; u < 8; ++u)
    gHreg[u] = *(const bf16x8*)(GpkH + ((size_t)(w*8 + u)*64 + l)*8);

  bGl[t] = gbout[t]; bGl[t+512] = gbout[t+512];
  XR[pl*36 + o] = xrel[pg*32 + o];
  {
    float hv = h[pg*32 + o]; float hsv;
    if (stage == 1)      hsv = hv;
    else if (stage == 2) hsv = fmaf(kh[pg*32+o], (1.f/3.f), hv);
    else if (stage == 3) hsv = hv - (1.f/3.f)*kh[pg*32+o] + kh[NPS + pg*32+o];
    else                 hsv = hv + kh[pg*32+o] - kh[NPS + pg*32+o] + kh[2*NPS + pg*32+o];
    HS[pl*34 + o] = hsv;
  }

  // ---- phase A: agg MFMA (A hi+lo, x hi only) ----
  {
    f32x4 acc0 = {0.f,0.f,0.f,0.f}, acc1 = {0.f,0.f,0.f,0.f};
    #pragma unroll
    for (int cc = 0; cc < 2; ++cc) {
      int c = w*2 + cc;
      size_t aoff = ((size_t)(ntile*16 + c)*64 + l)*8;
      bf16x8 aH = *(const bf16x8*)(ApkH + aoff);
      bf16x8 aL = *(const bf16x8*)(ApkL + aoff);
      size_t boff0 = (((size_t)(b*16 + c)*2 + 0)*64 + l)*8;
      bf16x8 bH0 = *(const bf16x8*)(xpkH + boff0);
      bf16x8 bH1 = *(const bf16x8*)(xpkH + boff0 + 512);
      acc0 = __builtin_amdgcn_mfma_f32_16x16x32_bf16(aL, bH0, acc0, 0, 0, 0);
      acc0 = __builtin_amdgcn_mfma_f32_16x16x32_bf16(aH, bH0, acc0, 0, 0, 0);
      acc1 = __builtin_amdgcn_mfma_f32_16x16x32_bf16(aL, bH1, acc1, 0, 0, 0);
      acc1 = __builtin_amdgcn_mfma_f32_16x16x32_bf16(aH, bH1, acc1, 0, 0, 0);
    }
    #pragma unroll
    for (int r = 0; r < 4; ++r) {
      scrA[w][lg*4+r][ll]      = acc0[r];
      scrA[w][lg*4+r][16 + ll] = acc1[r];
    }
  }
  __syncthreads();   // bar1

  // ---- phase B: chain (w0/w1, in-wave) | AG+pool (w4-7, in-wave) ----
  if (w < 2) {
    {
      bf16x8 aH = pack_hi(&HS[ll*34 + lg*8]);
      #pragma unroll
      for (int tile = 0; tile < 2; ++tile) {
        bf16x8 bH = *(const bf16x8*)(WpkH + (size_t)tile*512 + l*8);
        bf16x8 bL = *(const bf16x8*)(WpkL + (size_t)tile*512 + l*8);
        f32x4 acc = {0.f,0.f,0.f,0.f};
        acc = __builtin_amdgcn_mfma_f32_16x16x32_bf16(aH, bL, acc, 0, 0, 0);
        acc = __builtin_amdgcn_mfma_f32_16x16x32_bf16(aH, bH, acc, 0, 0, 0);
        int col = tile*16 + ll;
        float bb = fbin[col];
        #pragma unroll
        for (int r = 0; r < 4; ++r) X1[(lg*4+r)*34 + col] = fmaxf(acc[r] + bb, 0.f);
      }
    }
    {
      bf16x8 aH = pack_hi(&X1[ll*34 + lg*8]);
      #pragma unroll
      for (int tile = 0; tile < 2; ++tile) {
        bf16x8 bH = *(const bf16x8*)(WpkH + (size_t)(2+tile)*512 + l*8);
        bf16x8 bL = *(const bf16x8*)(WpkL + (size_t)(2+tile)*512 + l*8);
        f32x4 acc = {0.f,0.f,0.f,0.f};
        acc = __builtin_amdgcn_mfma_f32_16x16x32_bf16(aH, bL, acc, 0, 0, 0);
        acc = __builtin_amdgcn_mfma_f32_16x16x32_bf16(aH, bH, acc, 0, 0, 0);
        int col = tile*16 + ll;
        float bb = fbmid[col];
        #pragma unroll
        for (int r = 0; r < 4; ++r) X2[(lg*4+r)*34 + col] = fmaxf(acc[r] + bb, 0.f);
      }
    }
    {
      bf16x8 aH = pack_hi(&X2[ll*34 + lg*8]);
      float vf[2][4];
      #pragma unroll
      for (int e = 0; e < 2; ++e) {
        int T = 2*w + e;
        bf16x8 bH = *(const bf16x8*)(WpkH + (size_t)(4+T)*512 + l*8);
        bf16x8 bL = *(const bf16x8*)(WpkL + (size_t)(4+T)*512 + l*8);
        f32x4 acc = {0.f,0.f,0.f,0.f};
        acc = __builtin_amdgcn_mfma_f32_16x16x32_bf16(aH, bL, acc, 0, 0, 0);
        acc = __builtin_amdgcn_mfma_f32_16x16x32_bf16(aH, bH, acc, 0, 0, 0);
        int col = T*16 + ll;
        float bb = fbout[col];
        #pragma unroll
        for (int r = 0; r < 4; ++r) vf[e][r] = tanh_fast(acc[r] + bb);
      }
      float2 dxv[4];
      #pragma unroll
      for (int r = 0; r < 4; ++r)
        dxv[r] = *(const float2*)&dX[(size_t)slot*16384 + (size_t)(pgbase + lg*4 + r)*2];
      #pragma unroll
      for (int e = 0; e < 2; ++e) {
        int T = 2*w + e;
        float vo[4];
        #pragma unroll
        for (int r = 0; r < 4; ++r) vo[r] = __shfl_xor(vf[e][r], 1);
        if (!(l & 1)) {
          int hh = T*8 + (ll>>1);
          float4 dv;
          dv.x = vf[e][0]*dxv[0].x + vo[0]*dxv[0].y;
          dv.y = vf[e][1]*dxv[1].x + vo[1]*dxv[1].y;
          dv.z = vf[e][2]*dxv[2].x + vo[2]*dxv[2].y;
          dv.w = vf[e][3]*dxv[3].x + vo[3]*dxv[3].y;
          *(float4*)&DHT[hh*20 + lg*4] = dv;
        }
      }
    }
  } else if (w >= 4) {
    #pragma unroll
    for (int half = 0; half < 2; ++half) {
      int s = (t - 256) + half*256;
      int sp = s>>5, so = s&31;
      float v = 0.f;
      #pragma unroll
      for (int ww = 0; ww < 8; ++ww) v += scrA[ww][sp][so];
      AG[sp*36 + so] = v;
    }
    #pragma unroll
    for (int half = 0; half < 2; ++half) {
      int s = (t - 256) + half*256;
      int sp = s>>5, so = s&31;
      int nn = ntile*16 + sp;
      const unsigned* awp = awb + (size_t)nn*1024 + so;
      const float2* xr2 = (const float2*)&XR[sp*36];
      const float2* ag2 = (const float2*)&AG[sp*36];
      float acc = 0.f;
      #pragma unroll
      for (int q = 0; q < 16; ++q) {
        unsigned u = awp[q*32];
        float2 xv = xr2[q];
        acc = fmaf(xv.x, __uint_as_float(u << 16), acc);
        acc = fmaf(xv.y, __uint_as_float(u & 0xffff0000u), acc);
      }
      #pragma unroll
      for (int q = 0; q < 16; ++q) {
        unsigned u = awp[512 + q*32];
        float2 av = ag2[q];
        acc = fmaf(av.x, __uint_as_float(u << 16), acc);
        acc = fmaf(av.y, __uint_as_float(u & 0xffff0000u), acc);
      }
      PLb[sp*34 + so] = acc + ab[nn*32 + so];
    }
  }
  __syncthreads();   // bar2

  // ---- phase E: vg = tanh(PL@gWout + gbout), dz partial + shfl reduce ----
  {
    bf16x8 paH = pack_hi(&PLb[ll*34 + lg*8]);
    bf16x8 gLreg[8];
    #pragma unroll
    for (int u = 0; u < 8; ++u)
      gLreg[u] = *(const bf16x8*)(GpkL + ((size_t)(w*8 + u)*64 + l)*8);
    float p[4][4] = {{0.f,0.f,0.f,0.f},{0.f,0.f,0.f,0.f},{0.f,0.f,0.f,0.f},{0.f,0.f,0.f,0.f}};
    #pragma unroll
    for (int u = 0; u < 8; ++u) {
      f32x4 acc = {0.f,0.f,0.f,0.f};
      acc = __builtin_amdgcn_mfma_f32_16x16x32_bf16(paH, gLreg[u], acc, 0, 0, 0);
      acc = __builtin_amdgcn_mfma_f32_16x16x32_bf16(paH, gHreg[u], acc, 0, 0, 0);
      int tile = w*8 + u;
      int col = tile*16 + ll, oo = col & 31;
      float gb = bGl[col];
      float4 dh4 = *(const float4*)&DHT[oo*20 + lg*4];
      int h2 = u >> 1;
      float da[4] = {dh4.x, dh4.y, dh4.z, dh4.w};
      #pragma unroll
      for (int r = 0; r < 4; ++r) {
        float tv = tanh_fast(acc[r] + gb);
        p[r][h2] = fmaf(tv, da[r], p[r][h2]);
      }
    }
    #pragma unroll
    for (int r = 0; r < 4; ++r) {
      #pragma unroll
      for (int h2 = 0; h2 < 4; ++h2) {
        float v = p[r][h2];
        v += __shfl_xor(v, 1);
        v += __shfl_xor(v, 2);
        v += __shfl_xor(v, 4);
        v += __shfl_xor(v, 8);
        if (ll == r*4 + h2) DZ[(lg*4 + r)*33 + w*4 + h2] = v;
      }
    }
  }

  // ---- phase F (merged, no barrier): RK bookkeeping in OWN-WAVE DZ layout ----
  // wave w wrote DZ cols [w*4, w*4+4); thread reads (plF=l>>2, oF=w*4+(l&3)):
  // same-wave LDS program order makes this race-free without a barrier.
  {
    int plF = l >> 2;
    int oF = w*4 + (l & 3);
    int pgF = pgbase + plF;
    float dzv = DZ[plF*33 + oF];
    float dhv = DHT[oF*20 + plF];
    if (stage < 4) {
      kh[(size_t)(stage-1)*NPS + pgF*32 + oF] = dhv;
    } else {
      float hv = h[pgF*32+oF];
      float k1 = kh[pgF*32+oF], k2 = kh[NPS+pgF*32+oF], k3 = kh[2*NPS+pgF*32+oF];
      h[pgF*32+oF] = hv + 0.125f*(k1 + 3.f*(k2 + k3) + dhv);
    }
    float zv = z[pgF*32 + oF];
    float znv;
    if (stage == 1) {
      kz[pgF*32+oF] = dzv;
      znv = fmaf(dzv, (1.f/3.f), zv);
    } else if (stage == 2) {
      kz[NPS + pgF*32+oF] = dzv;
      znv = zv - (1.f/3.f)*kz[pgF*32+oF] + dzv;
    } else if (stage == 3) {
      kz[2*NPS + pgF*32+oF] = dzv;
      znv = zv + kz[pgF*32+oF] - kz[NPS+pgF*32+oF] + dzv;
    } else {
      float k1 = kz[pgF*32+oF], k2 = kz[NPS+pgF*32+oF], k3 = kz[2*NPS+pgF*32+oF];
      znv = zv + 0.125f*(k1 + 3.f*(k2 + k3) + dzv);
      z[pgF*32+oF] = znv;
    }
    X1[plF*34 + oF] = znv;   // X1 = z_next
  }
  __syncthreads();   // bar3

  if (!isLast) {
    // ---- phase G: xrel_next = relu(z_next@gWin+gbin); store f32 + packed hi ----
    if (w < 2) {
      bf16x8 aH = pack_hi(&X1[ll*34 + lg*8]);
      bf16x8 bH = *(const bf16x8*)(WpkH + (size_t)(8+w)*512 + l*8);
      bf16x8 bL = *(const bf16x8*)(WpkL + (size_t)(8+w)*512 + l*8);
      f32x4 acc = {0.f,0.f,0.f,0.f};
      acc = __builtin_amdgcn_mfma_f32_16x16x32_bf16(aH, bL, acc, 0, 0, 0);
      acc = __builtin_amdgcn_mfma_f32_16x16x32_bf16(aH, bH, acc, 0, 0, 0);
      int col = w*16 + ll;
      float bb = gbin[col];
      int hp = ntile & 1, cch = ntile >> 1;
      #pragma unroll
      for (int r = 0; r < 4; ++r) {
        float xr = fmaxf(acc[r] + bb, 0.f);
        int row = lg*4 + r;
        xrel[(size_t)(pgbase + row)*32 + col] = xr;
        int rr = hp*16 + row;
        size_t off = (((size_t)(b*16 + cch)*2 + w)*64 + ((rr>>3)*16 + ll))*8 + (rr&7);
        xpkHo[off] = (short)bf16h(xr);
      }
    }
  } else {
    // ---- fused conv-out: out[pg,oo] = sum_h z_final[h]*convW[oo,h] + convb[oo] ----
    if (t < 192) {
      int pl2 = t / 12, oo = t - pl2*12;
      const float* x1r = &X1[pl2*34];
      float s = convb[oo];
      #pragma unroll
      for (int hh2 = 0; hh2 < 32; ++hh2) s = fmaf(x1r[hh2], convW[oo*32 + hh2], s);
      out[(size_t)(pgbase + pl2)*12 + oo] = s;
    }
  }
}

extern "C" void kernel_launch(void* const* d_in, const int* in_sizes, int n_in,
                              void* d_out, int out_size, void* d_ws, size_t ws_size,
                              hipStream_t stream) {
  (void)in_sizes; (void)n_in; (void)out_size; (void)ws_size;
  const float* ca     = (const float*)d_in[1];
  const float* cb     = (const float*)d_in[2];
  const float* cc2    = (const float*)d_in[3];
  const float* cd3    = (const float*)d_in[4];
  const float* Wh     = (const float*)d_in[5];
  const float* bh     = (const float*)d_in[6];
  const float* Wz     = (const float*)d_in[7];
  const float* bz     = (const float*)d_in[8];
  const float* fWin   = (const float*)d_in[9];
  const float* fbin   = (const float*)d_in[10];
  const float* fWmid  = (const float*)d_in[11];
  const float* fbmid  = (const float*)d_in[12];
  const float* fWout  = (const float*)d_in[13];
  const float* fbout  = (const float*)d_in[14];
  const float* gWin   = (const float*)d_in[15];
  const float* gbin   = (const float*)d_in[16];
  const float* gE     = (const float*)d_in[17];
  const float* gWpool = (const float*)d_in[18];
  const float* gbpool = (const float*)d_in[19];
  const float* gWout  = (const float*)d_in[20];
  const float* gbout  = (const float*)d_in[21];
  const float* convW  = (const float*)d_in[22];
  const float* convb  = (const float*)d_in[23];
  float* out = (float*)d_out;

  float* wsf  = (float*)d_ws;
  unsigned* awb = (unsigned*)wsf;            // 524288 uints
  float* wAb  = wsf + 524288;                // 16384
  float* wDX  = wAb + 16384;                 // 557056
  float* wH   = wDX + 557056;                // 262144
  float* wZ   = wH + 262144;                 // 262144
  float* wKh  = wZ + 262144;                 // 786432
  float* wKz  = wKh + 786432;                // 786432
  float* wXr  = wKz + 786432;                // 262144
  short* ApkH = (short*)(wXr + 262144);      // 262144 shorts each below
  short* ApkL = ApkH + 262144;
  short* xp0H = ApkL + 262144;
  short* xp1H = xp0H + 262144;
  short* GpkH = xp1H + 262144;               // 32768
  short* GpkL = GpkH + 32768;                // 32768
  short* WpkH = GpkL + 32768;                // 5120
  short* WpkL = WpkH + 5120;                 // 5120

  kA_softmax<<<512, 256, 0, stream>>>(gE, ApkH, ApkL);
  kAwB<<<512, 256, 0, stream>>>(gE, gWpool, gbpool, awb, wAb);
  kPrep<<<2324, 256, 0, stream>>>(cb, cc2, cd3, wDX, gWout, GpkH, GpkL,
                                  fWin, fWmid, fWout, gWin, WpkH, WpkL);
  kInit<<<1024, 256, 0, stream>>>(ca, Wh, bh, Wz, bz, wH, wZ);
  kXrel0<<<1024, 256, 0, stream>>>(wZ, gWin, gbin, wXr, xp0H);

  for (int ss = 0; ss < 44; ++ss) {
    int stage = (ss & 3) + 1;
    int step = ss >> 2;
    int slot = (ss == 0) ? 0 : (3*step + (ss & 3));
    const short* xiH = (ss & 1) ? xp1H : xp0H;
    short* xoH = (ss & 1) ? xp0H : xp1H;
    kBF<<<512, 512, 0, stream>>>(awb, wAb, wDX, wH, wZ, wKh, wKz, wXr,
                                 ApkH, ApkL, xiH, xoH, GpkH, GpkL,
                                 WpkH, WpkL, fbin, fbmid, fbout, gbin, gbout,
                                 convW, convb, out, stage, slot, (ss == 43) ? 1 : 0);
  }
}